// Round 5
// baseline (411.178 us; speedup 1.0000x reference)
//
#include <hip/hip_runtime.h>
#include <hip/hip_bf16.h>

#define B_ 16
#define N_ 256
#define D_ 512
#define H_ 8
#define DK_ 64

typedef unsigned short u16;

__device__ __forceinline__ float bf2f(u16 u) {
    union { unsigned int i; float f; } v;
    v.i = ((unsigned int)u) << 16;
    return v.f;
}
__device__ __forceinline__ u16 f2bf(float f) {
    union { float f; unsigned int i; } v;
    v.f = f;
    unsigned int x = v.i;
    unsigned int r = (x >> 16) & 1u;
    x += 0x7fffu + r;           // round-to-nearest-even
    return (u16)(x >> 16);
}

// ---------------------------------------------------------------------------
// k_proj: C = A(f32 [4096,512]) @ W(f32 [512,512]) + b, written as bf16 to
// out[B*H, N, DK] layout. 64x64 tile, BK=16, 256 thr, 4x4 microtile.
// ---------------------------------------------------------------------------
__global__ __launch_bounds__(256) void k_proj(const float* __restrict__ A,
                                              const float* __restrict__ W,
                                              const float* __restrict__ bias,
                                              u16* __restrict__ out) {
    __shared__ float As[16][64];   // [k][m]
    __shared__ float Bs[16][64];   // [k][n]
    const int tid = threadIdx.x;
    const int m0 = blockIdx.y * 64;
    const int n0 = blockIdx.x * 64;
    const int tx = tid & 15, ty = tid >> 4;
    const int am = tid >> 2, ak = (tid & 3) * 4;   // A: row am, 4 k's
    const int bk = tid >> 4, bn = (tid & 15) * 4;  // W: row bk, 4 n's
    float c[4][4] = {};
    for (int k0 = 0; k0 < 512; k0 += 16) {
        float4 av = *reinterpret_cast<const float4*>(&A[(size_t)(m0 + am) * 512 + k0 + ak]);
        float4 bv = *reinterpret_cast<const float4*>(&W[(size_t)(k0 + bk) * 512 + n0 + bn]);
        As[ak + 0][am] = av.x; As[ak + 1][am] = av.y;
        As[ak + 2][am] = av.z; As[ak + 3][am] = av.w;
        Bs[bk][bn + 0] = bv.x; Bs[bk][bn + 1] = bv.y;
        Bs[bk][bn + 2] = bv.z; Bs[bk][bn + 3] = bv.w;
        __syncthreads();
#pragma unroll
        for (int kk = 0; kk < 16; ++kk) {
            float4 a = *reinterpret_cast<const float4*>(&As[kk][ty * 4]);
            float4 b = *reinterpret_cast<const float4*>(&Bs[kk][tx * 4]);
            float ar[4] = {a.x, a.y, a.z, a.w};
            float br[4] = {b.x, b.y, b.z, b.w};
#pragma unroll
            for (int i = 0; i < 4; ++i)
#pragma unroll
                for (int j = 0; j < 4; ++j) c[i][j] += ar[i] * br[j];
        }
        __syncthreads();
    }
#pragma unroll
    for (int j = 0; j < 4; ++j) {
        int col = n0 + tx * 4 + j;
        float bb = bias[col];
        int h = col >> 6, dk = col & 63;
#pragma unroll
        for (int i = 0; i < 4; ++i) {
            int m = m0 + ty * 4 + i;
            int b = m >> 8, row = m & 255;
            out[(size_t)(((b * H_ + h) * N_ + row)) * DK_ + dk] = f2bf(c[i][j] + bb);
        }
    }
}

// ---------------------------------------------------------------------------
// k_attn: fused geo-bias + QK^T + softmax + PV per (i-tile of 32, bh).
// S never hits global memory. LDS: 57.9 KB -> 2 blocks/CU.
// ---------------------------------------------------------------------------
__global__ __launch_bounds__(256) void k_attn(const u16* __restrict__ qh,
                                              const u16* __restrict__ kh,
                                              const u16* __restrict__ vh,
                                              const float* __restrict__ box,
                                              const float* __restrict__ Wg,
                                              const float* __restrict__ bgp,
                                              float* __restrict__ attn) {
    __shared__ float sS[32][256];    // 32 KB: bias -> logits -> probs
    __shared__ float sQf[64][32];    // 8 KB : Q tile, [dk][i]
    __shared__ u16   sKT[64][64];    // 8 KB : K chunk, [dk][j]
    __shared__ u16   sVt[64][64];    // 8 KB : V chunk, [j][dk]
    __shared__ float sWg[64];

    const int tid = threadIdx.x;
    const int i0 = blockIdx.x * 32;
    const int bh = blockIdx.y;
    const int b = bh >> 3, h = bh & 7;
    const int tx = tid & 15, ty = tid >> 4;
    const int lane = tid & 63, wid = tid >> 6;

    if (tid < 64) sWg[tid] = Wg[h * 64 + tid];
#pragma unroll
    for (int r = 0; r < 2; ++r) {
        int p = r * 256 + tid;           // < 512 (32 rows x 16 float4-chunks)
        int i = p >> 4;                  // 0..31
        int dk0 = (p & 15) * 4;
        ushort4 qv = *reinterpret_cast<const ushort4*>(
            &qh[((size_t)bh * N_ + i0 + i) * DK_ + dk0]);
        sQf[dk0 + 0][i] = bf2f(qv.x); sQf[dk0 + 1][i] = bf2f(qv.y);
        sQf[dk0 + 2][i] = bf2f(qv.z); sQf[dk0 + 3][i] = bf2f(qv.w);
    }
    // per-thread column-box (j = tid) precompute
    float4 bxj = *reinterpret_cast<const float4*>(&box[(size_t)(b * N_ + tid) * 4]);
    float cxj = (bxj.x + bxj.z) * 0.5f, cyj = (bxj.y + bxj.w) * 0.5f;
    float wj = bxj.z - bxj.x + 1.0f, hj = bxj.w - bxj.y + 1.0f;
    float bgh = bgp[h];
    __syncthreads();

    const float dm[8] = {1.0f, 0.42169650342858224f, 0.1778279410038923f,
                         0.07498942093324559f, 0.03162277660168379f,
                         0.013335214321633241f, 0.005623413251903491f,
                         0.0023713737056616554f};
    // ---- phase 1: geometric log-bias into sS[r][j] ----
    for (int r = 0; r < 32; ++r) {
        float4 bxi = *reinterpret_cast<const float4*>(&box[(size_t)(b * N_ + i0 + r) * 4]);
        float cxi = (bxi.x + bxi.z) * 0.5f, cyi = (bxi.y + bxi.w) * 0.5f;
        float wi = bxi.z - bxi.x + 1.0f, hi = bxi.w - bxi.y + 1.0f;
        float pos[4];
        pos[0] = __logf(fmaxf(fabsf((cxi - cxj) / wi), 1e-3f));
        pos[1] = __logf(fmaxf(fabsf((cyi - cyj) / hi), 1e-3f));
        pos[2] = __logf(wi / wj);
        pos[3] = __logf(hi / hj);
        float acc = bgh;
#pragma unroll
        for (int t = 0; t < 4; ++t) {
            float base = 100.0f * pos[t];
#pragma unroll
            for (int f = 0; f < 8; ++f) {
                float sn, cs;
                __sincosf(base * dm[f], &sn, &cs);
                int idx = t * 8 + f;
                acc += sWg[idx] * sn + sWg[idx + 32] * cs;
            }
        }
        sS[r][tid] = __logf(fmaxf(acc, 1e-6f));  // relu+clip+log
    }
    __syncthreads();

    // ---- phase 2: sS += (Q K^T) / 8, in j-chunks of 64 ----
    for (int j0 = 0; j0 < 256; j0 += 64) {
#pragma unroll
        for (int r = 0; r < 4; ++r) {
            int p = r * 256 + tid;          // < 1024 (64 rows x 16 chunks)
            int j = p >> 4;                 // 0..63
            int dk0 = (p & 15) * 4;
            ushort4 kv = *reinterpret_cast<const ushort4*>(
                &kh[((size_t)bh * N_ + j0 + j) * DK_ + dk0]);
            sKT[dk0 + 0][j] = kv.x; sKT[dk0 + 1][j] = kv.y;
            sKT[dk0 + 2][j] = kv.z; sKT[dk0 + 3][j] = kv.w;
        }
        __syncthreads();
        float c[2][4] = {};
#pragma unroll 8
        for (int kk = 0; kk < 64; ++kk) {
            float a0 = sQf[kk][ty * 2 + 0];
            float a1 = sQf[kk][ty * 2 + 1];
            ushort4 bv = *reinterpret_cast<const ushort4*>(&sKT[kk][tx * 4]);
            float b0 = bf2f(bv.x), b1 = bf2f(bv.y), b2 = bf2f(bv.z), b3 = bf2f(bv.w);
            c[0][0] += a0 * b0; c[0][1] += a0 * b1; c[0][2] += a0 * b2; c[0][3] += a0 * b3;
            c[1][0] += a1 * b0; c[1][1] += a1 * b1; c[1][2] += a1 * b2; c[1][3] += a1 * b3;
        }
#pragma unroll
        for (int ii = 0; ii < 2; ++ii)
#pragma unroll
            for (int jj = 0; jj < 4; ++jj)
                sS[ty * 2 + ii][j0 + tx * 4 + jj] += c[ii][jj] * 0.125f;
        __syncthreads();
    }

    // ---- phase 3: row softmax (each wave owns a row, 4 vals/lane) ----
#pragma unroll
    for (int rr = 0; rr < 8; ++rr) {
        int row = rr * 4 + wid;
        float4 x = *reinterpret_cast<float4*>(&sS[row][lane * 4]);
        float mx = fmaxf(fmaxf(x.x, x.y), fmaxf(x.z, x.w));
#pragma unroll
        for (int off = 32; off >= 1; off >>= 1) mx = fmaxf(mx, __shfl_xor(mx, off, 64));
        float e0 = __expf(x.x - mx), e1 = __expf(x.y - mx);
        float e2 = __expf(x.z - mx), e3 = __expf(x.w - mx);
        float s = e0 + e1 + e2 + e3;
#pragma unroll
        for (int off = 32; off >= 1; off >>= 1) s += __shfl_xor(s, off, 64);
        float inv = 1.0f / s;
        float4 p4 = {e0 * inv, e1 * inv, e2 * inv, e3 * inv};
        *reinterpret_cast<float4*>(&sS[row][lane * 4]) = p4;
    }
    __syncthreads();

    // ---- phase 4: O = P V, in j-chunks of 64 ----
    float o[2][4] = {};
    for (int j0 = 0; j0 < 256; j0 += 64) {
#pragma unroll
        for (int r = 0; r < 4; ++r) {
            int p = r * 256 + tid;          // < 1024 (64 rows x 16 chunks)
            int j = p >> 4;                 // 0..63
            int d0 = (p & 15) * 4;
            ushort4 vv = *reinterpret_cast<const ushort4*>(
                &vh[((size_t)bh * N_ + j0 + j) * DK_ + d0]);
            *reinterpret_cast<ushort4*>(&sVt[j][d0]) = vv;
        }
        __syncthreads();
#pragma unroll 8
        for (int jj = 0; jj < 64; ++jj) {
            ushort4 vv = *reinterpret_cast<const ushort4*>(&sVt[jj][tx * 4]);
            float v0 = bf2f(vv.x), v1 = bf2f(vv.y), v2 = bf2f(vv.z), v3 = bf2f(vv.w);
            float p0 = sS[ty * 2 + 0][j0 + jj];
            float p1 = sS[ty * 2 + 1][j0 + jj];
            o[0][0] += p0 * v0; o[0][1] += p0 * v1; o[0][2] += p0 * v2; o[0][3] += p0 * v3;
            o[1][0] += p1 * v0; o[1][1] += p1 * v1; o[1][2] += p1 * v2; o[1][3] += p1 * v3;
        }
        __syncthreads();
    }
#pragma unroll
    for (int ii = 0; ii < 2; ++ii) {
        float4 st = {o[ii][0], o[ii][1], o[ii][2], o[ii][3]};
        *reinterpret_cast<float4*>(
            &attn[(size_t)(b * N_ + i0 + ty * 2 + ii) * D_ + h * 64 + tx * 4]) = st;
    }
}

// ---------------------------------------------------------------------------
// k_out: out(f32 [4096,512]) = attn(f32) @ Wo(f32) + bo
// ---------------------------------------------------------------------------
__global__ __launch_bounds__(256) void k_out(const float* __restrict__ A,
                                             const float* __restrict__ W,
                                             const float* __restrict__ bias,
                                             float* __restrict__ out) {
    __shared__ float As[16][64];   // [k][m]
    __shared__ float Bs[16][64];   // [k][n]
    const int tid = threadIdx.x;
    const int m0 = blockIdx.y * 64;
    const int n0 = blockIdx.x * 64;
    const int tx = tid & 15, ty = tid >> 4;
    const int am = tid >> 2, ak = (tid & 3) * 4;
    const int bk = tid >> 4, bn = (tid & 15) * 4;
    float c[4][4] = {};
    for (int k0 = 0; k0 < 512; k0 += 16) {
        float4 av = *reinterpret_cast<const float4*>(&A[(size_t)(m0 + am) * 512 + k0 + ak]);
        float4 bv = *reinterpret_cast<const float4*>(&W[(size_t)(k0 + bk) * 512 + n0 + bn]);
        As[ak + 0][am] = av.x; As[ak + 1][am] = av.y;
        As[ak + 2][am] = av.z; As[ak + 3][am] = av.w;
        Bs[bk][bn + 0] = bv.x; Bs[bk][bn + 1] = bv.y;
        Bs[bk][bn + 2] = bv.z; Bs[bk][bn + 3] = bv.w;
        __syncthreads();
#pragma unroll
        for (int kk = 0; kk < 16; ++kk) {
            float4 a = *reinterpret_cast<const float4*>(&As[kk][ty * 4]);
            float4 b = *reinterpret_cast<const float4*>(&Bs[kk][tx * 4]);
            float ar[4] = {a.x, a.y, a.z, a.w};
            float br[4] = {b.x, b.y, b.z, b.w};
#pragma unroll
            for (int i = 0; i < 4; ++i)
#pragma unroll
                for (int j = 0; j < 4; ++j) c[i][j] += ar[i] * br[j];
        }
        __syncthreads();
    }
#pragma unroll
    for (int i = 0; i < 4; ++i)
#pragma unroll
        for (int j = 0; j < 4; ++j) {
            int col = n0 + tx * 4 + j;
            out[(size_t)(m0 + ty * 4 + i) * 512 + col] = c[i][j] + bias[col];
        }
}

extern "C" void kernel_launch(void* const* d_in, const int* in_sizes, int n_in,
                              void* d_out, int out_size, void* d_ws, size_t ws_size,
                              hipStream_t stream) {
    const float* Xq = (const float*)d_in[0];
    const float* Xk = (const float*)d_in[1];
    const float* Xv = (const float*)d_in[2];
    const float* box = (const float*)d_in[3];
    const float* Wq = (const float*)d_in[4];
    const float* bq = (const float*)d_in[5];
    const float* Wk = (const float*)d_in[6];
    const float* bk = (const float*)d_in[7];
    const float* Wv = (const float*)d_in[8];
    const float* bv = (const float*)d_in[9];
    const float* Wo = (const float*)d_in[10];
    const float* bo = (const float*)d_in[11];
    const float* Wg = (const float*)d_in[12];
    const float* bg = (const float*)d_in[13];
    float* out = (float*)d_out;

    // workspace (20 MB total): qh/kh/vh bf16 [B*H,N,64] (4 MB each), attn f32 (8 MB)
    u16* qh = (u16*)d_ws;
    u16* kh = qh + 2097152;
    u16* vh = kh + 2097152;
    float* attn = (float*)(vh + 2097152);

    dim3 blk(256);
    k_proj<<<dim3(8, 64), blk, 0, stream>>>(Xq, Wq, bq, qh);
    k_proj<<<dim3(8, 64), blk, 0, stream>>>(Xk, Wk, bk, kh);
    k_proj<<<dim3(8, 64), blk, 0, stream>>>(Xv, Wv, bv, vh);
    k_attn<<<dim3(8, 128), blk, 0, stream>>>(qh, kh, vh, box, Wg, bg, attn);
    k_out<<<dim3(8, 64), blk, 0, stream>>>(attn, Wo, bo, out);
}

// Round 6
// 249.432 us; speedup vs baseline: 1.6485x; 1.6485x over previous
//
#include <hip/hip_runtime.h>
#include <hip/hip_bf16.h>

#define B_ 16
#define N_ 256
#define D_ 512
#define H_ 8
#define DK_ 64

typedef unsigned short u16;
typedef __attribute__((ext_vector_type(8))) short bf16x8;
typedef __attribute__((ext_vector_type(4))) float f32x4;

__device__ __forceinline__ float bf2f(u16 u) {
    union { unsigned int i; float f; } v;
    v.i = ((unsigned int)u) << 16;
    return v.f;
}
__device__ __forceinline__ u16 f2bf(float f) {
    union { float f; unsigned int i; } v;
    v.f = f;
    unsigned int x = v.i;
    unsigned int r = (x >> 16) & 1u;
    x += 0x7fffu + r;           // round-to-nearest-even
    return (u16)(x >> 16);
}

// ---------------------------------------------------------------------------
// k_trans: Wt[z][n][k] (bf16) = W_z[k][n] (f32), z in {q,k,v,o}. 32x32 LDS tiles.
// ---------------------------------------------------------------------------
__global__ __launch_bounds__(256) void k_trans(const float* __restrict__ W0,
                                               const float* __restrict__ W1,
                                               const float* __restrict__ W2,
                                               const float* __restrict__ W3,
                                               u16* __restrict__ Wt) {
    const float* W = (blockIdx.z == 0) ? W0 : (blockIdx.z == 1) ? W1
                     : (blockIdx.z == 2) ? W2 : W3;
    u16* dst = Wt + (size_t)blockIdx.z * 262144;
    __shared__ float t[32][33];
    const int tid = threadIdx.x;
    const int kb = blockIdx.y * 32, nb = blockIdx.x * 32;
#pragma unroll
    for (int r = 0; r < 4; ++r) {
        int p = r * 256 + tid;
        t[p >> 5][p & 31] = W[(size_t)(kb + (p >> 5)) * 512 + nb + (p & 31)];
    }
    __syncthreads();
#pragma unroll
    for (int r = 0; r < 4; ++r) {
        int p = r * 256 + tid;
        dst[(size_t)(nb + (p >> 5)) * 512 + kb + (p & 31)] = f2bf(t[p & 31][p >> 5]);
    }
}

// ---------------------------------------------------------------------------
// k_gemm_qkv: MFMA bf16 GEMM. C[4096,512] = A(f32)@Wt^T + b, written bf16 to
// [B*H, N, DK] layout. BM=64, BN=128, BK=32; 4 waves, 32x64 per wave.
// ---------------------------------------------------------------------------
__global__ __launch_bounds__(256) void k_gemm_qkv(const float* __restrict__ A,
                                                  const u16* __restrict__ Wt,
                                                  const float* __restrict__ bias,
                                                  u16* __restrict__ outp) {
    __shared__ u16 As[64][40];    // [m][k] bf16, pad 40
    __shared__ u16 Bs[128][40];   // [n][k] bf16
    const int tid = threadIdx.x;
    const int m0 = blockIdx.y * 64, n0 = blockIdx.x * 128;
    const int wid = tid >> 6, lane = tid & 63;
    const int wm = (wid & 1) * 32, wn = (wid >> 1) * 64;
    const int lr = lane & 15, lk = (lane >> 4) * 8;
    f32x4 acc[2][4];
#pragma unroll
    for (int mi = 0; mi < 2; ++mi)
#pragma unroll
        for (int ni = 0; ni < 4; ++ni) acc[mi][ni] = (f32x4){0.f, 0.f, 0.f, 0.f};
    for (int k0 = 0; k0 < 512; k0 += 32) {
#pragma unroll
        for (int r = 0; r < 2; ++r) {
            int p = r * 256 + tid;          // 512 chunks: 64 rows x 8
            int row = p >> 3, kc = (p & 7) * 4;
            float4 a = *(const float4*)&A[(size_t)(m0 + row) * 512 + k0 + kc];
            ushort4 ab;
            ab.x = f2bf(a.x); ab.y = f2bf(a.y); ab.z = f2bf(a.z); ab.w = f2bf(a.w);
            *(ushort4*)&As[row][kc] = ab;
        }
#pragma unroll
        for (int r = 0; r < 4; ++r) {
            int p = r * 256 + tid;          // 1024 chunks: 128 rows x 8
            int n = p >> 3, kc = (p & 7) * 4;
            *(ushort4*)&Bs[n][kc] = *(const ushort4*)&Wt[(size_t)(n0 + n) * 512 + k0 + kc];
        }
        __syncthreads();
        bf16x8 af[2], bfr[4];
#pragma unroll
        for (int mi = 0; mi < 2; ++mi) af[mi] = *(const bf16x8*)&As[wm + mi * 16 + lr][lk];
#pragma unroll
        for (int ni = 0; ni < 4; ++ni) bfr[ni] = *(const bf16x8*)&Bs[wn + ni * 16 + lr][lk];
#pragma unroll
        for (int mi = 0; mi < 2; ++mi)
#pragma unroll
            for (int ni = 0; ni < 4; ++ni)
                acc[mi][ni] = __builtin_amdgcn_mfma_f32_16x16x32_bf16(
                    af[mi], bfr[ni], acc[mi][ni], 0, 0, 0);
        __syncthreads();
    }
#pragma unroll
    for (int mi = 0; mi < 2; ++mi)
#pragma unroll
        for (int ni = 0; ni < 4; ++ni) {
            int n = n0 + wn + ni * 16 + lr;
            float bb = bias[n];
            int h = n >> 6, dk = n & 63;
#pragma unroll
            for (int reg = 0; reg < 4; ++reg) {
                int m = m0 + wm + mi * 16 + (lane >> 4) * 4 + reg;
                int b = m >> 8, rr = m & 255;
                outp[(((size_t)(b * H_ + h) * N_) + rr) * DK_ + dk] =
                    f2bf(acc[mi][ni][reg] + bb);
            }
        }
}

// ---------------------------------------------------------------------------
// k_gemm_out: MFMA bf16 GEMM. out(f32 [4096,512]) = attnb(bf16)@Wot^T + bo.
// ---------------------------------------------------------------------------
__global__ __launch_bounds__(256) void k_gemm_out(const u16* __restrict__ Ab,
                                                  const u16* __restrict__ Wt,
                                                  const float* __restrict__ bias,
                                                  float* __restrict__ outp) {
    __shared__ u16 As[64][40];
    __shared__ u16 Bs[128][40];
    const int tid = threadIdx.x;
    const int m0 = blockIdx.y * 64, n0 = blockIdx.x * 128;
    const int wid = tid >> 6, lane = tid & 63;
    const int wm = (wid & 1) * 32, wn = (wid >> 1) * 64;
    const int lr = lane & 15, lk = (lane >> 4) * 8;
    f32x4 acc[2][4];
#pragma unroll
    for (int mi = 0; mi < 2; ++mi)
#pragma unroll
        for (int ni = 0; ni < 4; ++ni) acc[mi][ni] = (f32x4){0.f, 0.f, 0.f, 0.f};
    for (int k0 = 0; k0 < 512; k0 += 32) {
#pragma unroll
        for (int r = 0; r < 2; ++r) {
            int p = r * 256 + tid;
            int row = p >> 3, kc = (p & 7) * 4;
            *(ushort4*)&As[row][kc] = *(const ushort4*)&Ab[(size_t)(m0 + row) * 512 + k0 + kc];
        }
#pragma unroll
        for (int r = 0; r < 4; ++r) {
            int p = r * 256 + tid;
            int n = p >> 3, kc = (p & 7) * 4;
            *(ushort4*)&Bs[n][kc] = *(const ushort4*)&Wt[(size_t)(n0 + n) * 512 + k0 + kc];
        }
        __syncthreads();
        bf16x8 af[2], bfr[4];
#pragma unroll
        for (int mi = 0; mi < 2; ++mi) af[mi] = *(const bf16x8*)&As[wm + mi * 16 + lr][lk];
#pragma unroll
        for (int ni = 0; ni < 4; ++ni) bfr[ni] = *(const bf16x8*)&Bs[wn + ni * 16 + lr][lk];
#pragma unroll
        for (int mi = 0; mi < 2; ++mi)
#pragma unroll
            for (int ni = 0; ni < 4; ++ni)
                acc[mi][ni] = __builtin_amdgcn_mfma_f32_16x16x32_bf16(
                    af[mi], bfr[ni], acc[mi][ni], 0, 0, 0);
        __syncthreads();
    }
#pragma unroll
    for (int mi = 0; mi < 2; ++mi)
#pragma unroll
        for (int ni = 0; ni < 4; ++ni) {
            int n = n0 + wn + ni * 16 + lr;
            float bb = bias[n];
#pragma unroll
            for (int reg = 0; reg < 4; ++reg) {
                int m = m0 + wm + mi * 16 + (lane >> 4) * 4 + reg;
                outp[(size_t)m * 512 + n] = acc[mi][ni][reg] + bb;
            }
        }
}

// ---------------------------------------------------------------------------
// k_geo: trig computed ONCE per (b,i,j), dotted with all 8 heads.
// Writes log(clip(relu(wg),1e-6)) bf16 to Sg[B,H,N,N].
// ---------------------------------------------------------------------------
__global__ __launch_bounds__(256) void k_geo(const float* __restrict__ box,
                                             const float* __restrict__ Wg,
                                             const float* __restrict__ bg,
                                             u16* __restrict__ Sg) {
    __shared__ float sWg[8][64];
    __shared__ float sbg[8];
    const int tid = threadIdx.x;
    if (tid < 8) sbg[tid] = bg[tid];
    { int e = tid; sWg[e >> 6][e & 63] = Wg[e];
      e = tid + 256; sWg[e >> 6][e & 63] = Wg[e]; }
    const int bi = blockIdx.x, b = bi >> 8, i = bi & 255;
    float4 bxi = *(const float4*)&box[(size_t)bi * 4];
    float4 bxj = *(const float4*)&box[(size_t)(b * N_ + tid) * 4];
    __syncthreads();
    float cxi = (bxi.x + bxi.z) * 0.5f, cyi = (bxi.y + bxi.w) * 0.5f;
    float wi = bxi.z - bxi.x + 1.0f, hi = bxi.w - bxi.y + 1.0f;
    float cxj = (bxj.x + bxj.z) * 0.5f, cyj = (bxj.y + bxj.w) * 0.5f;
    float wj = bxj.z - bxj.x + 1.0f, hj = bxj.w - bxj.y + 1.0f;
    float pos[4];
    pos[0] = __logf(fmaxf(fabsf((cxi - cxj) / wi), 1e-3f));
    pos[1] = __logf(fmaxf(fabsf((cyi - cyj) / hi), 1e-3f));
    pos[2] = __logf(wi / wj);
    pos[3] = __logf(hi / hj);
    const float dm[8] = {1.0f, 0.42169650342858224f, 0.1778279410038923f,
                         0.07498942093324559f, 0.03162277660168379f,
                         0.013335214321633241f, 0.005623413251903491f,
                         0.0023713737056616554f};
    float acc[8];
#pragma unroll
    for (int h = 0; h < 8; ++h) acc[h] = sbg[h];
#pragma unroll
    for (int t = 0; t < 4; ++t) {
        float base = 100.0f * pos[t];
#pragma unroll
        for (int f = 0; f < 8; ++f) {
            float sn, cs;
            __sincosf(base * dm[f], &sn, &cs);
            int idx = t * 8 + f;
#pragma unroll
            for (int h = 0; h < 8; ++h)
                acc[h] += sWg[h][idx] * sn + sWg[h][idx + 32] * cs;
        }
    }
#pragma unroll
    for (int h = 0; h < 8; ++h)
        Sg[(((size_t)(b * H_ + h) * N_) + i) * N_ + tid] =
            f2bf(__logf(fmaxf(acc[h], 1e-6f)));
}

// ---------------------------------------------------------------------------
// k_attn: bias(from Sg) + QK^T/8 + softmax + PV. i-tile 16, f32 K/V in LDS,
// padded conflict-free layouts. LDS 38.4 KB -> 4 blocks/CU. Writes attn bf16.
// ---------------------------------------------------------------------------
__global__ __launch_bounds__(256) void k_attn(const u16* __restrict__ qh,
                                              const u16* __restrict__ kh,
                                              const u16* __restrict__ vh,
                                              const u16* __restrict__ Sg,
                                              u16* __restrict__ attnb) {
    __shared__ float sS[16][260];    // 16.6 KB, logits/probs (stride 260: 16B-aligned rows)
    __shared__ float sQ[64][17];     // 4.3 KB, Q [dk][i]
    __shared__ float sKV[64 * 68];   // 17.4 KB, K as [dk*68+j], V as [j*68+d]
    const int tid = threadIdx.x;
    const int i0 = blockIdx.x * 16;
    const int bh = blockIdx.y;
    const int b = bh >> 3, h = bh & 7;
    const int tx = tid & 15, ty = tid >> 4;     // ty = row (16), tx*4 = col group
    const int lane = tid & 63, wid = tid >> 6;

    // ---- stage Q tile [dk][i] (1024 elems, 1 ushort4/thread) ----
    {
        int i = tid >> 4, dk0 = (tid & 15) * 4;
        ushort4 qv = *(const ushort4*)&qh[((size_t)bh * N_ + i0 + i) * DK_ + dk0];
        sQ[dk0 + 0][i] = bf2f(qv.x); sQ[dk0 + 1][i] = bf2f(qv.y);
        sQ[dk0 + 2][i] = bf2f(qv.z); sQ[dk0 + 3][i] = bf2f(qv.w);
    }
    // ---- stage bias tile from Sg (16 x 256 bf16) ----
#pragma unroll
    for (int r = 0; r < 4; ++r) {
        int p = r * 256 + tid;
        int row = p >> 6, jc = (p & 63) * 4;
        ushort4 gv = *(const ushort4*)&Sg[(((size_t)(b * H_ + h) * N_) + i0 + row) * N_ + jc];
        float4 bv = {bf2f(gv.x), bf2f(gv.y), bf2f(gv.z), bf2f(gv.w)};
        *(float4*)&sS[row][jc] = bv;
    }
    __syncthreads();

    // ---- phase 2: sS += (Q K^T)/8, j-chunks of 64; K staged as [dk][j] f32 ----
    for (int j0 = 0; j0 < 256; j0 += 64) {
#pragma unroll
        for (int r = 0; r < 4; ++r) {
            int p = r * 256 + tid;
            int j = p >> 4, dk0 = (p & 15) * 4;
            ushort4 kv = *(const ushort4*)&kh[((size_t)bh * N_ + j0 + j) * DK_ + dk0];
            sKV[(dk0 + 0) * 68 + j] = bf2f(kv.x);
            sKV[(dk0 + 1) * 68 + j] = bf2f(kv.y);
            sKV[(dk0 + 2) * 68 + j] = bf2f(kv.z);
            sKV[(dk0 + 3) * 68 + j] = bf2f(kv.w);
        }
        __syncthreads();
        float c0 = 0.f, c1 = 0.f, c2 = 0.f, c3 = 0.f;
#pragma unroll 8
        for (int kk = 0; kk < 64; ++kk) {
            float qv = sQ[kk][ty];
            float4 kv = *(const float4*)&sKV[kk * 68 + tx * 4];
            c0 += qv * kv.x; c1 += qv * kv.y; c2 += qv * kv.z; c3 += qv * kv.w;
        }
        float* srow = &sS[ty][j0 + tx * 4];
        srow[0] += c0 * 0.125f; srow[1] += c1 * 0.125f;
        srow[2] += c2 * 0.125f; srow[3] += c3 * 0.125f;
        __syncthreads();
    }

    // ---- phase 3: row softmax (wave w owns rows {w,4+w,8+w,12+w}) ----
#pragma unroll
    for (int rr = 0; rr < 4; ++rr) {
        int row = rr * 4 + wid;
        float4 x = *(float4*)&sS[row][lane * 4];
        float mx = fmaxf(fmaxf(x.x, x.y), fmaxf(x.z, x.w));
#pragma unroll
        for (int off = 32; off >= 1; off >>= 1) mx = fmaxf(mx, __shfl_xor(mx, off, 64));
        float e0 = __expf(x.x - mx), e1 = __expf(x.y - mx);
        float e2 = __expf(x.z - mx), e3 = __expf(x.w - mx);
        float s = e0 + e1 + e2 + e3;
#pragma unroll
        for (int off = 32; off >= 1; off >>= 1) s += __shfl_xor(s, off, 64);
        float inv = 1.0f / s;
        float4 p4 = {e0 * inv, e1 * inv, e2 * inv, e3 * inv};
        *(float4*)&sS[row][lane * 4] = p4;
    }
    __syncthreads();

    // ---- phase 4: O = P V, V staged as [j][d] f32 ----
    float o0 = 0.f, o1 = 0.f, o2 = 0.f, o3 = 0.f;
    for (int j0 = 0; j0 < 256; j0 += 64) {
#pragma unroll
        for (int r = 0; r < 4; ++r) {
            int p = r * 256 + tid;
            int j = p >> 4, d0 = (p & 15) * 4;
            ushort4 vv = *(const ushort4*)&vh[((size_t)bh * N_ + j0 + j) * DK_ + d0];
            float4 vf = {bf2f(vv.x), bf2f(vv.y), bf2f(vv.z), bf2f(vv.w)};
            *(float4*)&sKV[j * 68 + d0] = vf;
        }
        __syncthreads();
#pragma unroll 8
        for (int jj = 0; jj < 64; ++jj) {
            float pv = sS[ty][j0 + jj];
            float4 vv = *(const float4*)&sKV[jj * 68 + tx * 4];
            o0 += pv * vv.x; o1 += pv * vv.y; o2 += pv * vv.z; o3 += pv * vv.w;
        }
        __syncthreads();
    }
    ushort4 st;
    st.x = f2bf(o0); st.y = f2bf(o1); st.z = f2bf(o2); st.w = f2bf(o3);
    *(ushort4*)&attnb[((size_t)(b * N_ + i0 + ty)) * D_ + h * 64 + tx * 4] = st;
}

extern "C" void kernel_launch(void* const* d_in, const int* in_sizes, int n_in,
                              void* d_out, int out_size, void* d_ws, size_t ws_size,
                              hipStream_t stream) {
    const float* Xq = (const float*)d_in[0];
    const float* Xk = (const float*)d_in[1];
    const float* Xv = (const float*)d_in[2];
    const float* box = (const float*)d_in[3];
    const float* Wq = (const float*)d_in[4];
    const float* bq = (const float*)d_in[5];
    const float* Wk = (const float*)d_in[6];
    const float* bk = (const float*)d_in[7];
    const float* Wv = (const float*)d_in[8];
    const float* bv = (const float*)d_in[9];
    const float* Wo = (const float*)d_in[10];
    const float* bo = (const float*)d_in[11];
    const float* Wg = (const float*)d_in[12];
    const float* bg = (const float*)d_in[13];
    float* out = (float*)d_out;

    // ws layout (u16 units): qh 0, kh 2M, vh 4M, attnb 6M, Sg 8M (8.39M elems),
    // Wt 16,777,216 (4x262144). Total ~35.7 MB.
    u16* ws16 = (u16*)d_ws;
    u16* qh = ws16;
    u16* kh = ws16 + 2097152;
    u16* vh = ws16 + 4194304;
    u16* attnb = ws16 + 6291456;
    u16* Sg = ws16 + 8388608;
    u16* Wt = ws16 + 16777216;

    dim3 blk(256);
    k_trans<<<dim3(16, 16, 4), blk, 0, stream>>>(Wq, Wk, Wv, Wo, Wt);
    k_gemm_qkv<<<dim3(4, 64), blk, 0, stream>>>(Xq, Wt + 0 * 262144, bq, qh);
    k_gemm_qkv<<<dim3(4, 64), blk, 0, stream>>>(Xk, Wt + 1 * 262144, bk, kh);
    k_gemm_qkv<<<dim3(4, 64), blk, 0, stream>>>(Xv, Wt + 2 * 262144, bv, vh);
    k_geo<<<dim3(B_ * N_), blk, 0, stream>>>(box, Wg, bg, Sg);
    k_attn<<<dim3(16, 128), blk, 0, stream>>>(qh, kh, vh, Sg, attnb);
    k_gemm_out<<<dim3(4, 64), blk, 0, stream>>>(attnb, Wt + 3 * 262144, bo, out);
}

// Round 7
// 222.949 us; speedup vs baseline: 1.8443x; 1.1188x over previous
//
#include <hip/hip_runtime.h>
#include <hip/hip_bf16.h>

#define B_ 16
#define N_ 256
#define D_ 512
#define H_ 8
#define DK_ 64

typedef unsigned short u16;
typedef __attribute__((ext_vector_type(8))) short bf16x8;
typedef __attribute__((ext_vector_type(4))) float f32x4;

__device__ __forceinline__ float bf2f(u16 u) {
    union { unsigned int i; float f; } v;
    v.i = ((unsigned int)u) << 16;
    return v.f;
}
__device__ __forceinline__ u16 f2bf(float f) {
    union { float f; unsigned int i; } v;
    v.f = f;
    unsigned int x = v.i;
    unsigned int r = (x >> 16) & 1u;
    x += 0x7fffu + r;           // round-to-nearest-even
    return (u16)(x >> 16);
}

// ---------------------------------------------------------------------------
// k_cvt: Xb[z] (bf16) = X_z (f32), z in {q,k,v}. 8 elems/thread.
// ---------------------------------------------------------------------------
__global__ __launch_bounds__(256) void k_cvt(const float* __restrict__ X0,
                                             const float* __restrict__ X1,
                                             const float* __restrict__ X2,
                                             u16* __restrict__ Xb) {
    const float* X = (blockIdx.y == 0) ? X0 : (blockIdx.y == 1) ? X1 : X2;
    u16* dst = Xb + (size_t)blockIdx.y * 2097152;
    int base = (blockIdx.x * 256 + threadIdx.x) * 8;
    float4 a = *(const float4*)&X[base];
    float4 b = *(const float4*)&X[base + 4];
    ushort4 oa, ob;
    oa.x = f2bf(a.x); oa.y = f2bf(a.y); oa.z = f2bf(a.z); oa.w = f2bf(a.w);
    ob.x = f2bf(b.x); ob.y = f2bf(b.y); ob.z = f2bf(b.z); ob.w = f2bf(b.w);
    *(ushort4*)&dst[base] = oa;
    *(ushort4*)&dst[base + 4] = ob;
}

// ---------------------------------------------------------------------------
// k_trans: Wt[z][n][k] (bf16) = W_z[k][n] (f32), z in {q,k,v,o}.
// ---------------------------------------------------------------------------
__global__ __launch_bounds__(256) void k_trans(const float* __restrict__ W0,
                                               const float* __restrict__ W1,
                                               const float* __restrict__ W2,
                                               const float* __restrict__ W3,
                                               u16* __restrict__ Wt) {
    const float* W = (blockIdx.z == 0) ? W0 : (blockIdx.z == 1) ? W1
                     : (blockIdx.z == 2) ? W2 : W3;
    u16* dst = Wt + (size_t)blockIdx.z * 262144;
    __shared__ float t[32][33];
    const int tid = threadIdx.x;
    const int kb = blockIdx.y * 32, nb = blockIdx.x * 32;
#pragma unroll
    for (int r = 0; r < 4; ++r) {
        int p = r * 256 + tid;
        t[p >> 5][p & 31] = W[(size_t)(kb + (p >> 5)) * 512 + nb + (p & 31)];
    }
    __syncthreads();
#pragma unroll
    for (int r = 0; r < 4; ++r) {
        int p = r * 256 + tid;
        dst[(size_t)(nb + (p >> 5)) * 512 + kb + (p & 31)] = f2bf(t[p & 31][p >> 5]);
    }
}

// ---------------------------------------------------------------------------
// Shared MFMA GEMM core: BM=64, BN=64, BK=64, 256 thr, wave tile 32x32,
// register prefetch of next K-tile. A [4096,512] bf16, Wt [n][k] bf16.
// ---------------------------------------------------------------------------
#define GEMM_CORE(Ab, Wt)                                                     \
    __shared__ u16 As[64][72];                                                \
    __shared__ u16 Bs[64][72];                                                \
    const int tid = threadIdx.x;                                              \
    const int n0 = blockIdx.x * 64, m0 = blockIdx.y * 64;                     \
    const int wid = tid >> 6, lane = tid & 63;                                \
    const int wm = (wid & 1) * 32, wn = (wid >> 1) * 32;                      \
    const int lr = lane & 15, lk8 = (lane >> 4) * 8;                          \
    const int srow = tid >> 2, sc4 = (tid & 3) * 16;  /* unused alt */        \
    (void)srow; (void)sc4;                                                    \
    f32x4 acc[2][2];                                                          \
    _Pragma("unroll") for (int mi = 0; mi < 2; ++mi)                          \
        _Pragma("unroll") for (int ni = 0; ni < 2; ++ni)                      \
            acc[mi][ni] = (f32x4){0.f, 0.f, 0.f, 0.f};                        \
    ushort4 ra[4], rb[4];                                                     \
    _Pragma("unroll") for (int r = 0; r < 4; ++r) {                           \
        int p = r * 256 + tid, row = p >> 4, c4 = (p & 15) * 4;               \
        ra[r] = *(const ushort4*)&Ab[(size_t)(m0 + row) * 512 + c4];          \
        rb[r] = *(const ushort4*)&Wt[(size_t)(n0 + row) * 512 + c4];          \
    }                                                                         \
    for (int it = 0; it < 8; ++it) {                                          \
        _Pragma("unroll") for (int r = 0; r < 4; ++r) {                       \
            int p = r * 256 + tid, row = p >> 4, c4 = (p & 15) * 4;           \
            *(ushort4*)&As[row][c4] = ra[r];                                  \
            *(ushort4*)&Bs[row][c4] = rb[r];                                  \
        }                                                                     \
        __syncthreads();                                                      \
        if (it < 7) {                                                         \
            int k0n = (it + 1) * 64;                                          \
            _Pragma("unroll") for (int r = 0; r < 4; ++r) {                   \
                int p = r * 256 + tid, row = p >> 4, c4 = (p & 15) * 4;       \
                ra[r] = *(const ushort4*)&Ab[(size_t)(m0 + row) * 512 + k0n + c4]; \
                rb[r] = *(const ushort4*)&Wt[(size_t)(n0 + row) * 512 + k0n + c4]; \
            }                                                                 \
        }                                                                     \
        _Pragma("unroll") for (int ks = 0; ks < 64; ks += 32) {               \
            bf16x8 af[2], bf[2];                                              \
            _Pragma("unroll") for (int mi = 0; mi < 2; ++mi)                  \
                af[mi] = *(const bf16x8*)&As[wm + mi * 16 + lr][ks + lk8];    \
            _Pragma("unroll") for (int ni = 0; ni < 2; ++ni)                  \
                bf[ni] = *(const bf16x8*)&Bs[wn + ni * 16 + lr][ks + lk8];    \
            _Pragma("unroll") for (int mi = 0; mi < 2; ++mi)                  \
                _Pragma("unroll") for (int ni = 0; ni < 2; ++ni)              \
                    acc[mi][ni] = __builtin_amdgcn_mfma_f32_16x16x32_bf16(    \
                        af[mi], bf[ni], acc[mi][ni], 0, 0, 0);                \
        }                                                                     \
        __syncthreads();                                                      \
    }

// k_gemm_qkv: z selects (X, W, bias, dst); out bf16 scattered to [B*H,N,DK].
__global__ __launch_bounds__(256) void k_gemm_qkv(const u16* __restrict__ Xb,
                                                  const u16* __restrict__ Wtb,
                                                  const float* __restrict__ bq,
                                                  const float* __restrict__ bk,
                                                  const float* __restrict__ bv,
                                                  u16* __restrict__ qkv) {
    const int z = blockIdx.z;
    const u16* Ab = Xb + (size_t)z * 2097152;
    const u16* Wt = Wtb + (size_t)z * 262144;
    const float* bias = (z == 0) ? bq : (z == 1) ? bk : bv;
    u16* outp = qkv + (size_t)z * 2097152;
    GEMM_CORE(Ab, Wt)
#pragma unroll
    for (int mi = 0; mi < 2; ++mi)
#pragma unroll
        for (int ni = 0; ni < 2; ++ni) {
            int col = n0 + wn + ni * 16 + lr;
            float bb = bias[col];
            int h = col >> 6, dk = col & 63;
#pragma unroll
            for (int reg = 0; reg < 4; ++reg) {
                int m = m0 + wm + mi * 16 + (lane >> 4) * 4 + reg;
                int b = m >> 8, rr = m & 255;
                outp[(((size_t)(b * H_ + h) * N_) + rr) * DK_ + dk] =
                    f2bf(acc[mi][ni][reg] + bb);
            }
        }
}

// k_gemm_out: out(f32) = attnb(bf16) @ Wot^T + bo.
__global__ __launch_bounds__(256) void k_gemm_out(const u16* __restrict__ Ab,
                                                  const u16* __restrict__ Wt,
                                                  const float* __restrict__ bias,
                                                  float* __restrict__ outp) {
    GEMM_CORE(Ab, Wt)
#pragma unroll
    for (int mi = 0; mi < 2; ++mi)
#pragma unroll
        for (int ni = 0; ni < 2; ++ni) {
            int col = n0 + wn + ni * 16 + lr;
            float bb = bias[col];
#pragma unroll
            for (int reg = 0; reg < 4; ++reg) {
                int m = m0 + wm + mi * 16 + (lane >> 4) * 4 + reg;
                outp[(size_t)m * 512 + col] = acc[mi][ni][reg] + bb;
            }
        }
}

// ---------------------------------------------------------------------------
// k_geo: trig once per (b,i,j), dotted with all 8 heads; bf16 log-bias out.
// ---------------------------------------------------------------------------
__global__ __launch_bounds__(256) void k_geo(const float* __restrict__ box,
                                             const float* __restrict__ Wg,
                                             const float* __restrict__ bg,
                                             u16* __restrict__ Sg) {
    __shared__ float sWg[8][64];
    __shared__ float sbg[8];
    const int tid = threadIdx.x;
    if (tid < 8) sbg[tid] = bg[tid];
    { int e = tid; sWg[e >> 6][e & 63] = Wg[e];
      e = tid + 256; sWg[e >> 6][e & 63] = Wg[e]; }
    const int bi = blockIdx.x, b = bi >> 8, i = bi & 255;
    float4 bxi = *(const float4*)&box[(size_t)bi * 4];
    float4 bxj = *(const float4*)&box[(size_t)(b * N_ + tid) * 4];
    __syncthreads();
    float cxi = (bxi.x + bxi.z) * 0.5f, cyi = (bxi.y + bxi.w) * 0.5f;
    float wi = bxi.z - bxi.x + 1.0f, hi = bxi.w - bxi.y + 1.0f;
    float cxj = (bxj.x + bxj.z) * 0.5f, cyj = (bxj.y + bxj.w) * 0.5f;
    float wj = bxj.z - bxj.x + 1.0f, hj = bxj.w - bxj.y + 1.0f;
    float pos[4];
    pos[0] = __logf(fmaxf(fabsf((cxi - cxj) / wi), 1e-3f));
    pos[1] = __logf(fmaxf(fabsf((cyi - cyj) / hi), 1e-3f));
    pos[2] = __logf(wi / wj);
    pos[3] = __logf(hi / hj);
    const float dm[8] = {1.0f, 0.42169650342858224f, 0.1778279410038923f,
                         0.07498942093324559f, 0.03162277660168379f,
                         0.013335214321633241f, 0.005623413251903491f,
                         0.0023713737056616554f};
    float acc[8];
#pragma unroll
    for (int h = 0; h < 8; ++h) acc[h] = sbg[h];
#pragma unroll
    for (int t = 0; t < 4; ++t) {
        float base = 100.0f * pos[t];
#pragma unroll
        for (int f = 0; f < 8; ++f) {
            float sn, cs;
            __sincosf(base * dm[f], &sn, &cs);
            int idx = t * 8 + f;
#pragma unroll
            for (int h = 0; h < 8; ++h)
                acc[h] += sWg[h][idx] * sn + sWg[h][idx + 32] * cs;
        }
    }
#pragma unroll
    for (int h = 0; h < 8; ++h)
        Sg[(((size_t)(b * H_ + h) * N_) + i) * N_ + tid] =
            f2bf(__logf(fmaxf(acc[h], 1e-6f)));
}

// ---------------------------------------------------------------------------
// k_attn: bias + QK^T/8 + softmax + PV. All LDS row-major, strided-j mapping
// => every LDS access <=2-way (free). LDS 38.3 KB -> 4 blocks/CU.
// ---------------------------------------------------------------------------
__global__ __launch_bounds__(256) void k_attn(const u16* __restrict__ qh,
                                              const u16* __restrict__ kh,
                                              const u16* __restrict__ vh,
                                              const u16* __restrict__ Sg,
                                              u16* __restrict__ attnb) {
    __shared__ float sS[16][260];    // logits/probs
    __shared__ float sQ[16 * 68];    // Q [i][dk]
    __shared__ float sKV[64 * 68];   // K or V chunk, [row][dk]
    const int tid = threadIdx.x;
    const int i0 = blockIdx.x * 16;
    const int bh = blockIdx.y;
    const int b = bh >> 3, h = bh & 7;
    const int tx = tid & 15, ty = tid >> 4;
    const int lane = tid & 63, wid = tid >> 6;

    // ---- stage Q tile [i][dk] (16x64 f32) ----
    {
        int i = tid >> 4, dk0 = (tid & 15) * 4;
        ushort4 qv = *(const ushort4*)&qh[((size_t)bh * N_ + i0 + i) * DK_ + dk0];
        float4 qf = {bf2f(qv.x), bf2f(qv.y), bf2f(qv.z), bf2f(qv.w)};
        *(float4*)&sQ[i * 68 + dk0] = qf;
    }
    // ---- stage bias tile from Sg (16 x 256 bf16) ----
#pragma unroll
    for (int r = 0; r < 4; ++r) {
        int p = r * 256 + tid;
        int row = p >> 6, jc = (p & 63) * 4;
        ushort4 gv = *(const ushort4*)&Sg[(((size_t)(b * H_ + h) * N_) + i0 + row) * N_ + jc];
        float4 bv = {bf2f(gv.x), bf2f(gv.y), bf2f(gv.z), bf2f(gv.w)};
        *(float4*)&sS[row][jc] = bv;
    }
    __syncthreads();

    // ---- phase 2: sS += (Q K^T)/8; K staged row-major, strided-j compute ----
    for (int j0 = 0; j0 < 256; j0 += 64) {
#pragma unroll
        for (int r = 0; r < 4; ++r) {
            int p = r * 256 + tid;
            int j = p >> 4, dk0 = (p & 15) * 4;
            ushort4 kv = *(const ushort4*)&kh[((size_t)bh * N_ + j0 + j) * DK_ + dk0];
            float4 kf = {bf2f(kv.x), bf2f(kv.y), bf2f(kv.z), bf2f(kv.w)};
            *(float4*)&sKV[j * 68 + dk0] = kf;
        }
        __syncthreads();
        float c0 = 0.f, c1 = 0.f, c2 = 0.f, c3 = 0.f;
#pragma unroll 4
        for (int dk0 = 0; dk0 < 64; dk0 += 4) {
            float4 q4 = *(const float4*)&sQ[ty * 68 + dk0];
            float4 k0v = *(const float4*)&sKV[(tx) * 68 + dk0];
            float4 k1v = *(const float4*)&sKV[(tx + 16) * 68 + dk0];
            float4 k2v = *(const float4*)&sKV[(tx + 32) * 68 + dk0];
            float4 k3v = *(const float4*)&sKV[(tx + 48) * 68 + dk0];
            c0 += q4.x * k0v.x + q4.y * k0v.y + q4.z * k0v.z + q4.w * k0v.w;
            c1 += q4.x * k1v.x + q4.y * k1v.y + q4.z * k1v.z + q4.w * k1v.w;
            c2 += q4.x * k2v.x + q4.y * k2v.y + q4.z * k2v.z + q4.w * k2v.w;
            c3 += q4.x * k3v.x + q4.y * k3v.y + q4.z * k3v.z + q4.w * k3v.w;
        }
        sS[ty][j0 + tx +  0] += c0 * 0.125f;
        sS[ty][j0 + tx + 16] += c1 * 0.125f;
        sS[ty][j0 + tx + 32] += c2 * 0.125f;
        sS[ty][j0 + tx + 48] += c3 * 0.125f;
        __syncthreads();
    }

    // ---- phase 3: row softmax (wave w owns rows {w,4+w,8+w,12+w}) ----
#pragma unroll
    for (int rr = 0; rr < 4; ++rr) {
        int row = rr * 4 + wid;
        float4 x = *(float4*)&sS[row][lane * 4];
        float mx = fmaxf(fmaxf(x.x, x.y), fmaxf(x.z, x.w));
#pragma unroll
        for (int off = 32; off >= 1; off >>= 1) mx = fmaxf(mx, __shfl_xor(mx, off, 64));
        float e0 = __expf(x.x - mx), e1 = __expf(x.y - mx);
        float e2 = __expf(x.z - mx), e3 = __expf(x.w - mx);
        float s = e0 + e1 + e2 + e3;
#pragma unroll
        for (int off = 32; off >= 1; off >>= 1) s += __shfl_xor(s, off, 64);
        float inv = 1.0f / s;
        float4 p4 = {e0 * inv, e1 * inv, e2 * inv, e3 * inv};
        *(float4*)&sS[row][lane * 4] = p4;
    }
    __syncthreads();

    // ---- phase 4: O = P V, V row-major [j][dk] ----
    float o0 = 0.f, o1 = 0.f, o2 = 0.f, o3 = 0.f;
    for (int j0 = 0; j0 < 256; j0 += 64) {
#pragma unroll
        for (int r = 0; r < 4; ++r) {
            int p = r * 256 + tid;
            int j = p >> 4, d0 = (p & 15) * 4;
            ushort4 vv = *(const ushort4*)&vh[((size_t)bh * N_ + j0 + j) * DK_ + d0];
            float4 vf = {bf2f(vv.x), bf2f(vv.y), bf2f(vv.z), bf2f(vv.w)};
            *(float4*)&sKV[j * 68 + d0] = vf;
        }
        __syncthreads();
#pragma unroll 8
        for (int jj = 0; jj < 64; ++jj) {
            float pv = sS[ty][j0 + jj];
            float4 vv = *(const float4*)&sKV[jj * 68 + tx * 4];
            o0 += pv * vv.x; o1 += pv * vv.y; o2 += pv * vv.z; o3 += pv * vv.w;
        }
        __syncthreads();
    }
    ushort4 st;
    st.x = f2bf(o0); st.y = f2bf(o1); st.z = f2bf(o2); st.w = f2bf(o3);
    *(ushort4*)&attnb[((size_t)(b * N_ + i0 + ty)) * D_ + h * 64 + tx * 4] = st;
}

extern "C" void kernel_launch(void* const* d_in, const int* in_sizes, int n_in,
                              void* d_out, int out_size, void* d_ws, size_t ws_size,
                              hipStream_t stream) {
    const float* Xq = (const float*)d_in[0];
    const float* Xk = (const float*)d_in[1];
    const float* Xv = (const float*)d_in[2];
    const float* box = (const float*)d_in[3];
    const float* Wq = (const float*)d_in[4];
    const float* bq = (const float*)d_in[5];
    const float* Wk = (const float*)d_in[6];
    const float* bk = (const float*)d_in[7];
    const float* Wv = (const float*)d_in[8];
    const float* bv = (const float*)d_in[9];
    const float* Wo = (const float*)d_in[10];
    const float* bo = (const float*)d_in[11];
    const float* Wg = (const float*)d_in[12];
    const float* bg = (const float*)d_in[13];
    float* out = (float*)d_out;

    // ws layout (u16 units), total 35.65 MB:
    //  [0,6M)        qh,kh,vh (contiguous: qkv buffer)
    //  [6M,14M)      Sg (8M)  -- Xb (6.29M) aliases this region (disjoint lifetime)
    //  [14M,16M)     attnb (2M)
    //  [16M,17M)     Wt (1M)
    u16* ws16 = (u16*)d_ws;
    u16* qkv = ws16;
    u16* qh = qkv;
    u16* kh = qkv + 2097152;
    u16* vh = qkv + 4194304;
    u16* Sg = ws16 + 6291456;
    u16* Xb = ws16 + 6291456;      // alias: dead before Sg is written
    u16* attnb = ws16 + 14680064;
    u16* Wt = ws16 + 16777216;

    dim3 blk(256);
    k_cvt<<<dim3(1024, 3), blk, 0, stream>>>(Xq, Xk, Xv, Xb);
    k_trans<<<dim3(16, 16, 4), blk, 0, stream>>>(Wq, Wk, Wv, Wo, Wt);
    k_gemm_qkv<<<dim3(8, 64, 3), blk, 0, stream>>>(Xb, Wt, bq, bk, bv, qkv);
    k_geo<<<dim3(B_ * N_), blk, 0, stream>>>(box, Wg, bg, Sg);
    k_attn<<<dim3(16, 128), blk, 0, stream>>>(qh, kh, vh, Sg, attnb);
    k_gemm_out<<<dim3(8, 64), blk, 0, stream>>>(attnb, Wt + 3 * 262144, bo, out);
}

// Round 8
// 184.845 us; speedup vs baseline: 2.2244x; 1.2061x over previous
//
#include <hip/hip_runtime.h>
#include <hip/hip_bf16.h>

#define B_ 16
#define N_ 256
#define D_ 512
#define H_ 8
#define DK_ 64

typedef unsigned short u16;
typedef __attribute__((ext_vector_type(8))) short bf16x8;
typedef __attribute__((ext_vector_type(4))) float f32x4;

__device__ __forceinline__ float bf2f(u16 u) {
    union { unsigned int i; float f; } v;
    v.i = ((unsigned int)u) << 16;
    return v.f;
}
__device__ __forceinline__ u16 f2bf(float f) {
    union { float f; unsigned int i; } v;
    v.f = f;
    unsigned int x = v.i;
    unsigned int r = (x >> 16) & 1u;
    x += 0x7fffu + r;           // round-to-nearest-even
    return (u16)(x >> 16);
}

// ---------------------------------------------------------------------------
// k_prep: merged input-convert (blocks 0..3071) and weight-transpose
// (blocks 3072..4095).  cvt: Xb[z](bf16) = X_z(f32).  trans: Wt[z][n][k](bf16)
// = W_z[k][n](f32).
// ---------------------------------------------------------------------------
__global__ __launch_bounds__(256) void k_prep(const float* __restrict__ X0,
                                              const float* __restrict__ X1,
                                              const float* __restrict__ X2,
                                              u16* __restrict__ Xb,
                                              const float* __restrict__ W0,
                                              const float* __restrict__ W1,
                                              const float* __restrict__ W2,
                                              const float* __restrict__ W3,
                                              u16* __restrict__ Wt) {
    const int bid = blockIdx.x;
    const int tid = threadIdx.x;
    if (bid < 3072) {
        int z = bid >> 10, x = bid & 1023;
        const float* X = (z == 0) ? X0 : (z == 1) ? X1 : X2;
        u16* dst = Xb + (size_t)z * 2097152;
        int base = (x * 256 + tid) * 8;
        float4 a = *(const float4*)&X[base];
        float4 b = *(const float4*)&X[base + 4];
        ushort4 oa, ob;
        oa.x = f2bf(a.x); oa.y = f2bf(a.y); oa.z = f2bf(a.z); oa.w = f2bf(a.w);
        ob.x = f2bf(b.x); ob.y = f2bf(b.y); ob.z = f2bf(b.z); ob.w = f2bf(b.w);
        *(ushort4*)&dst[base] = oa;
        *(ushort4*)&dst[base + 4] = ob;
    } else {
        int t = bid - 3072;
        int z = t >> 8, yb = (t >> 4) & 15, xb = t & 15;
        const float* W = (z == 0) ? W0 : (z == 1) ? W1 : (z == 2) ? W2 : W3;
        u16* dst = Wt + (size_t)z * 262144;
        __shared__ float tt[32][33];
        const int kb = yb * 32, nb = xb * 32;
#pragma unroll
        for (int r = 0; r < 4; ++r) {
            int p = r * 256 + tid;
            tt[p >> 5][p & 31] = W[(size_t)(kb + (p >> 5)) * 512 + nb + (p & 31)];
        }
        __syncthreads();
#pragma unroll
        for (int r = 0; r < 4; ++r) {
            int p = r * 256 + tid;
            dst[(size_t)(nb + (p >> 5)) * 512 + kb + (p & 31)] = f2bf(tt[p & 31][p >> 5]);
        }
    }
}

// ---------------------------------------------------------------------------
// Double-buffered MFMA GEMM core: BM=BN=64, BK=64, 1 barrier per iteration.
// A[4096,512] bf16 row-major; Wt[n][k] bf16. Wave tile 32x32 (2x2 16x16 accs).
// ---------------------------------------------------------------------------
#define GEMM_CORE_DB(Ab, Wt)                                                  \
    __shared__ u16 As[2][64][72];                                             \
    __shared__ u16 Bs[2][64][72];                                             \
    const int tid = threadIdx.x;                                              \
    const int n0 = blockIdx.x * 64, m0 = blockIdx.y * 64;                     \
    const int wid = tid >> 6, lane = tid & 63;                                \
    const int wm = (wid & 1) * 32, wn = (wid >> 1) * 32;                      \
    const int lr = lane & 15, lk8 = (lane >> 4) * 8;                          \
    f32x4 acc[2][2];                                                          \
    _Pragma("unroll") for (int mi = 0; mi < 2; ++mi)                          \
        _Pragma("unroll") for (int ni = 0; ni < 2; ++ni)                      \
            acc[mi][ni] = (f32x4){0.f, 0.f, 0.f, 0.f};                        \
    ushort4 ra[4], rb[4];                                                     \
    _Pragma("unroll") for (int r = 0; r < 4; ++r) {                           \
        int p = r * 256 + tid, row = p >> 4, c4 = (p & 15) * 4;               \
        ra[r] = *(const ushort4*)&Ab[(size_t)(m0 + row) * 512 + c4];          \
        rb[r] = *(const ushort4*)&Wt[(size_t)(n0 + row) * 512 + c4];          \
    }                                                                         \
    _Pragma("unroll") for (int r = 0; r < 4; ++r) {                           \
        int p = r * 256 + tid, row = p >> 4, c4 = (p & 15) * 4;               \
        *(ushort4*)&As[0][row][c4] = ra[r];                                   \
        *(ushort4*)&Bs[0][row][c4] = rb[r];                                   \
    }                                                                         \
    __syncthreads();                                                          \
    for (int it = 0; it < 8; ++it) {                                          \
        const int cur = it & 1;                                               \
        if (it < 7) {                                                         \
            int k0n = (it + 1) * 64;                                          \
            _Pragma("unroll") for (int r = 0; r < 4; ++r) {                   \
                int p = r * 256 + tid, row = p >> 4, c4 = (p & 15) * 4;       \
                ra[r] = *(const ushort4*)&Ab[(size_t)(m0 + row) * 512 + k0n + c4]; \
                rb[r] = *(const ushort4*)&Wt[(size_t)(n0 + row) * 512 + k0n + c4]; \
            }                                                                 \
        }                                                                     \
        _Pragma("unroll") for (int ks = 0; ks < 64; ks += 32) {               \
            bf16x8 af[2], bfx[2];                                             \
            _Pragma("unroll") for (int mi = 0; mi < 2; ++mi)                  \
                af[mi] = *(const bf16x8*)&As[cur][wm + mi * 16 + lr][ks + lk8]; \
            _Pragma("unroll") for (int ni = 0; ni < 2; ++ni)                  \
                bfx[ni] = *(const bf16x8*)&Bs[cur][wn + ni * 16 + lr][ks + lk8]; \
            _Pragma("unroll") for (int mi = 0; mi < 2; ++mi)                  \
                _Pragma("unroll") for (int ni = 0; ni < 2; ++ni)              \
                    acc[mi][ni] = __builtin_amdgcn_mfma_f32_16x16x32_bf16(    \
                        af[mi], bfx[ni], acc[mi][ni], 0, 0, 0);               \
        }                                                                     \
        if (it < 7) {                                                         \
            _Pragma("unroll") for (int r = 0; r < 4; ++r) {                   \
                int p = r * 256 + tid, row = p >> 4, c4 = (p & 15) * 4;       \
                *(ushort4*)&As[1 - cur][row][c4] = ra[r];                     \
                *(ushort4*)&Bs[1 - cur][row][c4] = rb[r];                     \
            }                                                                 \
            __syncthreads();                                                  \
        }                                                                     \
    }

// k_gemm_qkv: z selects (X, W, bias, dst); out bf16 scattered to [B*H,N,DK].
__global__ __launch_bounds__(256) void k_gemm_qkv(const u16* __restrict__ Xb,
                                                  const u16* __restrict__ Wtb,
                                                  const float* __restrict__ bq,
                                                  const float* __restrict__ bk,
                                                  const float* __restrict__ bv,
                                                  u16* __restrict__ qkv) {
    const int z = blockIdx.z;
    const u16* Ab = Xb + (size_t)z * 2097152;
    const u16* Wt = Wtb + (size_t)z * 262144;
    const float* bias = (z == 0) ? bq : (z == 1) ? bk : bv;
    u16* outp = qkv + (size_t)z * 2097152;
    GEMM_CORE_DB(Ab, Wt)
#pragma unroll
    for (int mi = 0; mi < 2; ++mi)
#pragma unroll
        for (int ni = 0; ni < 2; ++ni) {
            int col = n0 + wn + ni * 16 + lr;
            float bb = bias[col];
            int h = col >> 6, dk = col & 63;
#pragma unroll
            for (int reg = 0; reg < 4; ++reg) {
                int m = m0 + wm + mi * 16 + (lane >> 4) * 4 + reg;
                int b = m >> 8, rr = m & 255;
                outp[(((size_t)(b * H_ + h) * N_) + rr) * DK_ + dk] =
                    f2bf(acc[mi][ni][reg] + bb);
            }
        }
}

// k_gemm_out: out(f32) = attnb(bf16) @ Wot^T + bo.
__global__ __launch_bounds__(256) void k_gemm_out(const u16* __restrict__ Ab,
                                                  const u16* __restrict__ Wt,
                                                  const float* __restrict__ bias,
                                                  float* __restrict__ outp) {
    GEMM_CORE_DB(Ab, Wt)
#pragma unroll
    for (int mi = 0; mi < 2; ++mi)
#pragma unroll
        for (int ni = 0; ni < 2; ++ni) {
            int col = n0 + wn + ni * 16 + lr;
            float bb = bias[col];
#pragma unroll
            for (int reg = 0; reg < 4; ++reg) {
                int m = m0 + wm + mi * 16 + (lane >> 4) * 4 + reg;
                outp[(size_t)m * 512 + col] = acc[mi][ni][reg] + bb;
            }
        }
}

// ---------------------------------------------------------------------------
// k_geo: trig once per (b,i,j), dotted with all 8 heads; bf16 log-bias out.
// ---------------------------------------------------------------------------
__global__ __launch_bounds__(256) void k_geo(const float* __restrict__ box,
                                             const float* __restrict__ Wg,
                                             const float* __restrict__ bg,
                                             u16* __restrict__ Sg) {
    __shared__ float sWg[8][64];
    __shared__ float sbg[8];
    const int tid = threadIdx.x;
    if (tid < 8) sbg[tid] = bg[tid];
    { int e = tid; sWg[e >> 6][e & 63] = Wg[e];
      e = tid + 256; sWg[e >> 6][e & 63] = Wg[e]; }
    const int bi = blockIdx.x, b = bi >> 8;
    float4 bxi = *(const float4*)&box[(size_t)bi * 4];
    float4 bxj = *(const float4*)&box[(size_t)(b * N_ + tid) * 4];
    __syncthreads();
    float cxi = (bxi.x + bxi.z) * 0.5f, cyi = (bxi.y + bxi.w) * 0.5f;
    float wi = bxi.z - bxi.x + 1.0f, hi = bxi.w - bxi.y + 1.0f;
    float cxj = (bxj.x + bxj.z) * 0.5f, cyj = (bxj.y + bxj.w) * 0.5f;
    float wj = bxj.z - bxj.x + 1.0f, hj = bxj.w - bxj.y + 1.0f;
    float pos[4];
    pos[0] = __logf(fmaxf(fabsf((cxi - cxj) / wi), 1e-3f));
    pos[1] = __logf(fmaxf(fabsf((cyi - cyj) / hi), 1e-3f));
    pos[2] = __logf(wi / wj);
    pos[3] = __logf(hi / hj);
    const float dm[8] = {1.0f, 0.42169650342858224f, 0.1778279410038923f,
                         0.07498942093324559f, 0.03162277660168379f,
                         0.013335214321633241f, 0.005623413251903491f,
                         0.0023713737056616554f};
    float acc[8];
#pragma unroll
    for (int h = 0; h < 8; ++h) acc[h] = sbg[h];
#pragma unroll
    for (int t = 0; t < 4; ++t) {
        float base = 100.0f * pos[t];
#pragma unroll
        for (int f = 0; f < 8; ++f) {
            float sn, cs;
            __sincosf(base * dm[f], &sn, &cs);
            int idx = t * 8 + f;
#pragma unroll
            for (int h = 0; h < 8; ++h)
                acc[h] += sWg[h][idx] * sn + sWg[h][idx + 32] * cs;
        }
    }
    const int i = bi & 255;
#pragma unroll
    for (int h = 0; h < 8; ++h)
        Sg[(((size_t)(b * H_ + h) * N_) + i) * N_ + tid] =
            f2bf(__logf(fmaxf(acc[h], 1e-6f)));
}

// ---------------------------------------------------------------------------
// k_attn: MFMA flash tile. Per block: (bh, 32 q-rows). QK^T and PV on matrix
// cores; S: accs -> LDS f32; P: bf16 LDS round-trip; V transposed in staging.
// LDS 58.4 KB (aliased regions) -> 2 blocks/CU.
// ---------------------------------------------------------------------------
__global__ __launch_bounds__(256) void k_attn(const u16* __restrict__ qh,
                                              const u16* __restrict__ kh,
                                              const u16* __restrict__ vh,
                                              const u16* __restrict__ Sg,
                                              u16* __restrict__ attnb) {
    __shared__ __align__(16) unsigned char smem[58368];
    u16* sQ = (u16*)smem;                       // [32][72] bf16 (4608 B)
    u16* sK = (u16*)(smem + 4608);              // [256][72] bf16 (36864 B)
    float* sS = (float*)(smem + 4608);          //  alias: [32][260] f32 (33280 B)
    u16* sVt = (u16*)(smem + 4608);             //  alias: [64][264] bf16 (33792 B)
    u16* sP = (u16*)(smem + 41472);             // [32][264] bf16 (16896 B)

    const int tid = threadIdx.x;
    const int i0 = blockIdx.x * 32;
    const int bh = blockIdx.y;
    const int b = bh >> 3, h = bh & 7;
    const int wid = tid >> 6, lane = tid & 63;
    const int lr = lane & 15, lk8 = (lane >> 4) * 8, quad4 = (lane >> 4) * 4;

    // ---- stage Q [32][72] and K [256][72] (straight bf16 copies) ----
#pragma unroll
    for (int r = 0; r < 2; ++r) {
        int p = r * 256 + tid, i = p >> 4, d0 = (p & 15) * 4;
        *(ushort4*)&sQ[i * 72 + d0] =
            *(const ushort4*)&qh[((size_t)bh * N_ + i0 + i) * DK_ + d0];
    }
#pragma unroll
    for (int r = 0; r < 16; ++r) {
        int p = r * 256 + tid, j = p >> 4, d0 = (p & 15) * 4;
        *(ushort4*)&sK[j * 72 + d0] =
            *(const ushort4*)&kh[((size_t)bh * N_ + j) * DK_ + d0];
    }
    __syncthreads();

    // ---- QK^T: wave w owns j-cols [w*64, w*64+64): 2 m-tiles x 4 n-tiles ----
    f32x4 acc[2][4];
#pragma unroll
    for (int mi = 0; mi < 2; ++mi)
#pragma unroll
        for (int ni = 0; ni < 4; ++ni) acc[mi][ni] = (f32x4){0.f, 0.f, 0.f, 0.f};
    const int wn = wid * 64;
#pragma unroll
    for (int ks = 0; ks < 64; ks += 32) {
        bf16x8 af[2], bfx[4];
#pragma unroll
        for (int mi = 0; mi < 2; ++mi)
            af[mi] = *(const bf16x8*)&sQ[(mi * 16 + lr) * 72 + ks + lk8];
#pragma unroll
        for (int ni = 0; ni < 4; ++ni)
            bfx[ni] = *(const bf16x8*)&sK[(wn + ni * 16 + lr) * 72 + ks + lk8];
#pragma unroll
        for (int mi = 0; mi < 2; ++mi)
#pragma unroll
            for (int ni = 0; ni < 4; ++ni)
                acc[mi][ni] = __builtin_amdgcn_mfma_f32_16x16x32_bf16(
                    af[mi], bfx[ni], acc[mi][ni], 0, 0, 0);
    }
    __syncthreads();   // K dead; sS may now overwrite it

    // ---- dump S = acc/8 + geo-bias into sS[32][260] ----
#pragma unroll
    for (int mi = 0; mi < 2; ++mi)
#pragma unroll
        for (int ni = 0; ni < 4; ++ni) {
            int col = wn + ni * 16 + lr;
#pragma unroll
            for (int reg = 0; reg < 4; ++reg) {
                int row = mi * 16 + quad4 + reg;
                float bias = bf2f(Sg[(((size_t)bh * N_) + i0 + row) * N_ + col]);
                sS[row * 260 + col] = acc[mi][ni][reg] * 0.125f + bias;
            }
        }
    __syncthreads();

    // ---- softmax per row; write P bf16 to sP[32][264] ----
#pragma unroll
    for (int rr = 0; rr < 8; ++rr) {
        int row = rr * 4 + wid;
        float4 x = *(float4*)&sS[row * 260 + lane * 4];
        float mx = fmaxf(fmaxf(x.x, x.y), fmaxf(x.z, x.w));
#pragma unroll
        for (int off = 32; off >= 1; off >>= 1) mx = fmaxf(mx, __shfl_xor(mx, off, 64));
        float e0 = __expf(x.x - mx), e1 = __expf(x.y - mx);
        float e2 = __expf(x.z - mx), e3 = __expf(x.w - mx);
        float s = e0 + e1 + e2 + e3;
#pragma unroll
        for (int off = 32; off >= 1; off >>= 1) s += __shfl_xor(s, off, 64);
        float inv = 1.0f / s;
        ushort4 p4;
        p4.x = f2bf(e0 * inv); p4.y = f2bf(e1 * inv);
        p4.z = f2bf(e2 * inv); p4.w = f2bf(e3 * inv);
        *(ushort4*)&sP[row * 264 + lane * 4] = p4;
    }
    __syncthreads();   // sS reads done; sVt may overwrite

    // ---- stage V^T [64][264] ----
#pragma unroll
    for (int r = 0; r < 16; ++r) {
        int p = r * 256 + tid, j = p >> 4, d0 = (p & 15) * 4;
        ushort4 vv = *(const ushort4*)&vh[((size_t)bh * N_ + j) * DK_ + d0];
        sVt[(d0 + 0) * 264 + j] = vv.x;
        sVt[(d0 + 1) * 264 + j] = vv.y;
        sVt[(d0 + 2) * 264 + j] = vv.z;
        sVt[(d0 + 3) * 264 + j] = vv.w;
    }
    __syncthreads();

    // ---- PV: wave w owns d-tile [w*16, w*16+16): 2 m-tiles, K=256 ----
    f32x4 acc2[2];
    acc2[0] = (f32x4){0.f, 0.f, 0.f, 0.f};
    acc2[1] = (f32x4){0.f, 0.f, 0.f, 0.f};
    const int wd = wid * 16;
#pragma unroll
    for (int ks8 = 0; ks8 < 8; ++ks8) {
        int k0 = ks8 * 32;
        bf16x8 bfx = *(const bf16x8*)&sVt[(wd + lr) * 264 + k0 + lk8];
#pragma unroll
        for (int mi = 0; mi < 2; ++mi) {
            bf16x8 af = *(const bf16x8*)&sP[(mi * 16 + lr) * 264 + k0 + lk8];
            acc2[mi] = __builtin_amdgcn_mfma_f32_16x16x32_bf16(af, bfx, acc2[mi], 0, 0, 0);
        }
    }
#pragma unroll
    for (int mi = 0; mi < 2; ++mi)
#pragma unroll
        for (int reg = 0; reg < 4; ++reg) {
            int row = mi * 16 + quad4 + reg;
            attnb[((size_t)(b * N_ + i0 + row)) * D_ + h * 64 + wd + lr] =
                f2bf(acc2[mi][reg]);
        }
}

extern "C" void kernel_launch(void* const* d_in, const int* in_sizes, int n_in,
                              void* d_out, int out_size, void* d_ws, size_t ws_size,
                              hipStream_t stream) {
    const float* Xq = (const float*)d_in[0];
    const float* Xk = (const float*)d_in[1];
    const float* Xv = (const float*)d_in[2];
    const float* box = (const float*)d_in[3];
    const float* Wq = (const float*)d_in[4];
    const float* bq = (const float*)d_in[5];
    const float* Wk = (const float*)d_in[6];
    const float* bk = (const float*)d_in[7];
    const float* Wv = (const float*)d_in[8];
    const float* bv = (const float*)d_in[9];
    const float* Wo = (const float*)d_in[10];
    const float* bo = (const float*)d_in[11];
    const float* Wg = (const float*)d_in[12];
    const float* bg = (const float*)d_in[13];
    float* out = (float*)d_out;

    // ws layout (u16 units), total 35.65 MB:
    //  [0,6M)     qkv (qh,kh,vh)
    //  [6M,14M)   Sg (8.39M) -- Xb (6.29M) aliases (Xb dead before Sg written)
    //  [14M,16M)  attnb
    //  [16M,17M)  Wt
    u16* ws16 = (u16*)d_ws;
    u16* qkv = ws16;
    u16* qh = qkv;
    u16* kh = qkv + 2097152;
    u16* vh = qkv + 4194304;
    u16* Sg = ws16 + 6291456;
    u16* Xb = ws16 + 6291456;
    u16* attnb = ws16 + 14680064;
    u16* Wt = ws16 + 16777216;

    dim3 blk(256);
    k_prep<<<dim3(4096), blk, 0, stream>>>(Xq, Xk, Xv, Xb, Wq, Wk, Wv, Wo, Wt);
    k_gemm_qkv<<<dim3(8, 64, 3), blk, 0, stream>>>(Xb, Wt, bq, bk, bv, qkv);
    k_geo<<<dim3(B_ * N_), blk, 0, stream>>>(box, Wg, bg, Sg);
    k_attn<<<dim3(8, 128), blk, 0, stream>>>(qh, kh, vh, Sg, attnb);
    k_gemm_out<<<dim3(8, 64), blk, 0, stream>>>(attnb, Wt + 3 * 262144, bo, out);
}

// Round 10
// 182.764 us; speedup vs baseline: 2.2498x; 1.0114x over previous
//
#include <hip/hip_runtime.h>
#include <hip/hip_bf16.h>

#define B_ 16
#define N_ 256
#define D_ 512
#define H_ 8
#define DK_ 64

typedef unsigned short u16;
typedef __attribute__((ext_vector_type(8))) short bf16x8;
typedef __attribute__((ext_vector_type(4))) float f32x4;

__device__ __forceinline__ float bf2f(u16 u) {
    union { unsigned int i; float f; } v;
    v.i = ((unsigned int)u) << 16;
    return v.f;
}
__device__ __forceinline__ u16 f2bf(float f) {
    union { float f; unsigned int i; } v;
    v.f = f;
    unsigned int x = v.i;
    unsigned int r = (x >> 16) & 1u;
    x += 0x7fffu + r;           // round-to-nearest-even
    return (u16)(x >> 16);
}

// ---------------------------------------------------------------------------
// k_wtrans: Wt[z][n][k] (bf16) = W_z[k][n] (f32), z in {q,k,v,o}.
// ---------------------------------------------------------------------------
__global__ __launch_bounds__(256) void k_wtrans(const float* __restrict__ W0,
                                                const float* __restrict__ W1,
                                                const float* __restrict__ W2,
                                                const float* __restrict__ W3,
                                                u16* __restrict__ Wt) {
    const float* W = (blockIdx.z == 0) ? W0 : (blockIdx.z == 1) ? W1
                     : (blockIdx.z == 2) ? W2 : W3;
    u16* dst = Wt + (size_t)blockIdx.z * 262144;
    __shared__ float t[32][33];
    const int tid = threadIdx.x;
    const int kb = blockIdx.y * 32, nb = blockIdx.x * 32;
#pragma unroll
    for (int r = 0; r < 4; ++r) {
        int p = r * 256 + tid;
        t[p >> 5][p & 31] = W[(size_t)(kb + (p >> 5)) * 512 + nb + (p & 31)];
    }
    __syncthreads();
#pragma unroll
    for (int r = 0; r < 4; ++r) {
        int p = r * 256 + tid;
        dst[(size_t)(nb + (p >> 5)) * 512 + kb + (p & 31)] = f2bf(t[p & 31][p >> 5]);
    }
}

// ---------------------------------------------------------------------------
// k_gemm_qkv: f32 X read directly (cvt in staging), dbuf BK=64 MFMA core,
// LDS-bounce epilogue for coalesced stores.
//   z=0: qh[bh][row][dk] = ((X Wq)+bq) * 0.125 (exact pow2 scale)
//   z=1: kh[bh][row][dk]
//   z=2: vhT[bh][dk][row]  (transposed for attn's PV B-operand)
// ---------------------------------------------------------------------------
__global__ __launch_bounds__(256) void k_gemm_qkv(const float* __restrict__ Xq,
                                                  const float* __restrict__ Xk,
                                                  const float* __restrict__ Xv,
                                                  const u16* __restrict__ Wtb,
                                                  const float* __restrict__ bq,
                                                  const float* __restrict__ bk,
                                                  const float* __restrict__ bv,
                                                  u16* __restrict__ qkv) {
    const int z = blockIdx.z;
    const float* A = (z == 0) ? Xq : (z == 1) ? Xk : Xv;
    const u16* Wt = Wtb + (size_t)z * 262144;
    const float* bias = (z == 0) ? bq : (z == 1) ? bk : bv;
    u16* dst = qkv + (size_t)z * 2097152;

    __shared__ u16 As[2][64][72];
    __shared__ u16 Bs[2][64][72];
    const int tid = threadIdx.x;
    const int n0 = blockIdx.x * 64, m0 = blockIdx.y * 64;
    const int wid = tid >> 6, lane = tid & 63;
    const int wm = (wid & 1) * 32, wn = (wid >> 1) * 32;
    const int lr = lane & 15, lk8 = (lane >> 4) * 8, quad4 = (lane >> 4) * 4;

    f32x4 acc[2][2];
#pragma unroll
    for (int mi = 0; mi < 2; ++mi)
#pragma unroll
        for (int ni = 0; ni < 2; ++ni) acc[mi][ni] = (f32x4){0.f, 0.f, 0.f, 0.f};

    float4 raf[4];
    ushort4 rb[4];
#pragma unroll
    for (int r = 0; r < 4; ++r) {
        int p = r * 256 + tid, row = p >> 4, c4 = (p & 15) * 4;
        raf[r] = *(const float4*)&A[(size_t)(m0 + row) * 512 + c4];
        rb[r] = *(const ushort4*)&Wt[(size_t)(n0 + row) * 512 + c4];
    }
#pragma unroll
    for (int r = 0; r < 4; ++r) {
        int p = r * 256 + tid, row = p >> 4, c4 = (p & 15) * 4;
        ushort4 ab;
        ab.x = f2bf(raf[r].x); ab.y = f2bf(raf[r].y);
        ab.z = f2bf(raf[r].z); ab.w = f2bf(raf[r].w);
        *(ushort4*)&As[0][row][c4] = ab;
        *(ushort4*)&Bs[0][row][c4] = rb[r];
    }
    __syncthreads();
    for (int it = 0; it < 8; ++it) {
        const int cur = it & 1;
        if (it < 7) {
            int k0n = (it + 1) * 64;
#pragma unroll
            for (int r = 0; r < 4; ++r) {
                int p = r * 256 + tid, row = p >> 4, c4 = (p & 15) * 4;
                raf[r] = *(const float4*)&A[(size_t)(m0 + row) * 512 + k0n + c4];
                rb[r] = *(const ushort4*)&Wt[(size_t)(n0 + row) * 512 + k0n + c4];
            }
        }
#pragma unroll
        for (int ks = 0; ks < 64; ks += 32) {
            bf16x8 af[2], bfx[2];
#pragma unroll
            for (int mi = 0; mi < 2; ++mi)
                af[mi] = *(const bf16x8*)&As[cur][wm + mi * 16 + lr][ks + lk8];
#pragma unroll
            for (int ni = 0; ni < 2; ++ni)
                bfx[ni] = *(const bf16x8*)&Bs[cur][wn + ni * 16 + lr][ks + lk8];
#pragma unroll
            for (int mi = 0; mi < 2; ++mi)
#pragma unroll
                for (int ni = 0; ni < 2; ++ni)
                    acc[mi][ni] = __builtin_amdgcn_mfma_f32_16x16x32_bf16(
                        af[mi], bfx[ni], acc[mi][ni], 0, 0, 0);
        }
        if (it < 7) {
#pragma unroll
            for (int r = 0; r < 4; ++r) {
                int p = r * 256 + tid, row = p >> 4, c4 = (p & 15) * 4;
                ushort4 ab;
                ab.x = f2bf(raf[r].x); ab.y = f2bf(raf[r].y);
                ab.z = f2bf(raf[r].z); ab.w = f2bf(raf[r].w);
                *(ushort4*)&As[1 - cur][row][c4] = ab;
                *(ushort4*)&Bs[1 - cur][row][c4] = rb[r];
            }
            __syncthreads();
        }
    }
    // ---- epilogue via LDS bounce (As[0] is safe to overwrite) ----
    u16* bounce = &As[0][0][0];   // [64][72]
    const float scale = (z == 0) ? 0.125f : 1.0f;
    const int h = n0 >> 6, b = m0 >> 8, rrb = m0 & 255;
    if (z == 2) {
        // transposed: bounce[cn][rm]
#pragma unroll
        for (int mi = 0; mi < 2; ++mi)
#pragma unroll
            for (int ni = 0; ni < 2; ++ni) {
                int cn = wn + ni * 16 + lr;
                float bb = bias[n0 + cn];
#pragma unroll
                for (int reg = 0; reg < 4; ++reg) {
                    int rm = wm + mi * 16 + quad4 + reg;
                    bounce[cn * 72 + rm] = f2bf(acc[mi][ni][reg] + bb);
                }
            }
        __syncthreads();
#pragma unroll
        for (int r = 0; r < 4; ++r) {
            int p = r * 256 + tid, dn = p >> 4, c4 = (p & 15) * 4;
            *(ushort4*)&dst[(((size_t)(b * H_ + h) * DK_) + dn) * N_ + rrb + c4] =
                *(const ushort4*)&bounce[dn * 72 + c4];
        }
    } else {
        // row-major: bounce[rm][cn]
#pragma unroll
        for (int mi = 0; mi < 2; ++mi)
#pragma unroll
            for (int ni = 0; ni < 2; ++ni) {
                int cn = wn + ni * 16 + lr;
                float bb = bias[n0 + cn];
#pragma unroll
                for (int reg = 0; reg < 4; ++reg) {
                    int rm = wm + mi * 16 + quad4 + reg;
                    bounce[rm * 72 + cn] = f2bf((acc[mi][ni][reg] + bb) * scale);
                }
            }
        __syncthreads();
#pragma unroll
        for (int r = 0; r < 4; ++r) {
            int p = r * 256 + tid, rm = p >> 4, c4 = (p & 15) * 4;
            *(ushort4*)&dst[(((size_t)(b * H_ + h) * N_) + rrb + rm) * DK_ + c4] =
                *(const ushort4*)&bounce[rm * 72 + c4];
        }
    }
}

// ---------------------------------------------------------------------------
// k_gemm_out: out(f32) = attnb(bf16) @ Wot^T + bo (dbuf core, f32 stores are
// already coalesced 64B/quad).
// ---------------------------------------------------------------------------
__global__ __launch_bounds__(256) void k_gemm_out(const u16* __restrict__ Ab,
                                                  const u16* __restrict__ Wt,
                                                  const float* __restrict__ bias,
                                                  float* __restrict__ outp) {
    __shared__ u16 As[2][64][72];
    __shared__ u16 Bs[2][64][72];
    const int tid = threadIdx.x;
    const int n0 = blockIdx.x * 64, m0 = blockIdx.y * 64;
    const int wid = tid >> 6, lane = tid & 63;
    const int wm = (wid & 1) * 32, wn = (wid >> 1) * 32;
    const int lr = lane & 15, lk8 = (lane >> 4) * 8;
    f32x4 acc[2][2];
#pragma unroll
    for (int mi = 0; mi < 2; ++mi)
#pragma unroll
        for (int ni = 0; ni < 2; ++ni) acc[mi][ni] = (f32x4){0.f, 0.f, 0.f, 0.f};
    ushort4 ra[4], rb[4];
#pragma unroll
    for (int r = 0; r < 4; ++r) {
        int p = r * 256 + tid, row = p >> 4, c4 = (p & 15) * 4;
        ra[r] = *(const ushort4*)&Ab[(size_t)(m0 + row) * 512 + c4];
        rb[r] = *(const ushort4*)&Wt[(size_t)(n0 + row) * 512 + c4];
    }
#pragma unroll
    for (int r = 0; r < 4; ++r) {
        int p = r * 256 + tid, row = p >> 4, c4 = (p & 15) * 4;
        *(ushort4*)&As[0][row][c4] = ra[r];
        *(ushort4*)&Bs[0][row][c4] = rb[r];
    }
    __syncthreads();
    for (int it = 0; it < 8; ++it) {
        const int cur = it & 1;
        if (it < 7) {
            int k0n = (it + 1) * 64;
#pragma unroll
            for (int r = 0; r < 4; ++r) {
                int p = r * 256 + tid, row = p >> 4, c4 = (p & 15) * 4;
                ra[r] = *(const ushort4*)&Ab[(size_t)(m0 + row) * 512 + k0n + c4];
                rb[r] = *(const ushort4*)&Wt[(size_t)(n0 + row) * 512 + k0n + c4];
            }
        }
#pragma unroll
        for (int ks = 0; ks < 64; ks += 32) {
            bf16x8 af[2], bfx[2];
#pragma unroll
            for (int mi = 0; mi < 2; ++mi)
                af[mi] = *(const bf16x8*)&As[cur][wm + mi * 16 + lr][ks + lk8];
#pragma unroll
            for (int ni = 0; ni < 2; ++ni)
                bfx[ni] = *(const bf16x8*)&Bs[cur][wn + ni * 16 + lr][ks + lk8];
#pragma unroll
            for (int mi = 0; mi < 2; ++mi)
#pragma unroll
                for (int ni = 0; ni < 2; ++ni)
                    acc[mi][ni] = __builtin_amdgcn_mfma_f32_16x16x32_bf16(
                        af[mi], bfx[ni], acc[mi][ni], 0, 0, 0);
        }
        if (it < 7) {
#pragma unroll
            for (int r = 0; r < 4; ++r) {
                int p = r * 256 + tid, row = p >> 4, c4 = (p & 15) * 4;
                *(ushort4*)&As[1 - cur][row][c4] = ra[r];
                *(ushort4*)&Bs[1 - cur][row][c4] = rb[r];
            }
            __syncthreads();
        }
    }
#pragma unroll
    for (int mi = 0; mi < 2; ++mi)
#pragma unroll
        for (int ni = 0; ni < 2; ++ni) {
            int col = n0 + wn + ni * 16 + lr;
            float bb = bias[col];
#pragma unroll
            for (int reg = 0; reg < 4; ++reg) {
                int m = m0 + wm + mi * 16 + (lane >> 4) * 4 + reg;
                outp[(size_t)m * 512 + col] = acc[mi][ni][reg] + bb;
            }
        }
}

// ---------------------------------------------------------------------------
// k_geo: trig once per (b,i,j), dotted with all 8 heads; bf16 log-bias out.
// ---------------------------------------------------------------------------
__global__ __launch_bounds__(256) void k_geo(const float* __restrict__ box,
                                             const float* __restrict__ Wg,
                                             const float* __restrict__ bg,
                                             u16* __restrict__ Sg) {
    __shared__ float sWg[8][64];
    __shared__ float sbg[8];
    const int tid = threadIdx.x;
    if (tid < 8) sbg[tid] = bg[tid];
    { int e = tid; sWg[e >> 6][e & 63] = Wg[e];
      e = tid + 256; sWg[e >> 6][e & 63] = Wg[e]; }
    const int bi = blockIdx.x, b = bi >> 8;
    float4 bxi = *(const float4*)&box[(size_t)bi * 4];
    float4 bxj = *(const float4*)&box[(size_t)(b * N_ + tid) * 4];
    __syncthreads();
    float cxi = (bxi.x + bxi.z) * 0.5f, cyi = (bxi.y + bxi.w) * 0.5f;
    float wi = bxi.z - bxi.x + 1.0f, hi = bxi.w - bxi.y + 1.0f;
    float cxj = (bxj.x + bxj.z) * 0.5f, cyj = (bxj.y + bxj.w) * 0.5f;
    float wj = bxj.z - bxj.x + 1.0f, hj = bxj.w - bxj.y + 1.0f;
    float pos[4];
    pos[0] = __logf(fmaxf(fabsf((cxi - cxj) / wi), 1e-3f));
    pos[1] = __logf(fmaxf(fabsf((cyi - cyj) / hi), 1e-3f));
    pos[2] = __logf(wi / wj);
    pos[3] = __logf(hi / hj);
    const float dm[8] = {1.0f, 0.42169650342858224f, 0.1778279410038923f,
                         0.07498942093324559f, 0.03162277660168379f,
                         0.013335214321633241f, 0.005623413251903491f,
                         0.0023713737056616554f};
    float acc[8];
#pragma unroll
    for (int h = 0; h < 8; ++h) acc[h] = sbg[h];
#pragma unroll
    for (int t = 0; t < 4; ++t) {
        float base = 100.0f * pos[t];
#pragma unroll
        for (int f = 0; f < 8; ++f) {
            float sn, cs;
            __sincosf(base * dm[f], &sn, &cs);
            int idx = t * 8 + f;
#pragma unroll
            for (int h = 0; h < 8; ++h)
                acc[h] += sWg[h][idx] * sn + sWg[h][idx + 32] * cs;
        }
    }
    const int i = bi & 255;
#pragma unroll
    for (int h = 0; h < 8; ++h)
        Sg[(((size_t)(b * H_ + h) * N_) + i) * N_ + tid] =
            f2bf(__logf(fmaxf(acc[h], 1e-6f)));
}

// ---------------------------------------------------------------------------
// k_attn v3: S in accumulators; in-register softmax (shuffle + 1KB LDS cross-
// wave reduce); bias preloaded; K/V in 128-chunks; V pre-transposed input.
// LDS 40,960 B -> 4 blocks/CU.
// ---------------------------------------------------------------------------
__global__ __launch_bounds__(256) void k_attn(const u16* __restrict__ qh,
                                              const u16* __restrict__ kh,
                                              const u16* __restrict__ vhT,
                                              const u16* __restrict__ Sg,
                                              u16* __restrict__ attnb) {
    __shared__ __align__(16) unsigned char smem[40960];
    u16* sQ = (u16*)smem;                     // [32][72]  (4608 B)
    u16* sP = (u16*)(smem + 4608);            // [32][264] (16896 B): bias -> P
    u16* sK = (u16*)(smem + 21504);           // [128][72] (18432 B), aliased:
    u16* sVt = (u16*)(smem + 21504);          // [64][136] (17408 B)
    float* sRedM = (float*)(smem + 39936);    // [32][4]
    float* sRedS = (float*)(smem + 40448);    // [32][4]

    const int tid = threadIdx.x;
    const int i0 = blockIdx.x * 32;
    const int bh = blockIdx.y;
    const int b = bh >> 3, h = bh & 7;
    const int wid = tid >> 6, lane = tid & 63;
    const int lr = lane & 15, lk8 = (lane >> 4) * 8, quad4 = (lane >> 4) * 4;

    // ---- stage Q, bias, K chunk 0 ----
#pragma unroll
    for (int r = 0; r < 2; ++r) {
        int p = r * 256 + tid, i = p >> 4, d0 = (p & 15) * 4;
        *(ushort4*)&sQ[i * 72 + d0] =
            *(const ushort4*)&qh[((size_t)bh * N_ + i0 + i) * DK_ + d0];
    }
#pragma unroll
    for (int r = 0; r < 8; ++r) {
        int p = r * 256 + tid, row = p >> 6, jc = (p & 63) * 4;
        *(ushort4*)&sP[row * 264 + jc] =
            *(const ushort4*)&Sg[(((size_t)bh * N_) + i0 + row) * N_ + jc];
    }
#pragma unroll
    for (int r = 0; r < 8; ++r) {
        int p = r * 256 + tid, j = p >> 4, d0 = (p & 15) * 4;
        *(ushort4*)&sK[j * 72 + d0] =
            *(const ushort4*)&kh[((size_t)bh * N_ + j) * DK_ + d0];
    }
    __syncthreads();

    // ---- K chunk-1 prefetch into regs; QK^T chunk 0 ----
    ushort4 kpre[8];
#pragma unroll
    for (int r = 0; r < 8; ++r) {
        int p = r * 256 + tid, j = p >> 4, d0 = (p & 15) * 4;
        kpre[r] = *(const ushort4*)&kh[((size_t)bh * N_ + 128 + j) * DK_ + d0];
    }
    f32x4 acc[2][2][2];   // [chunk][mi][ni]
#pragma unroll
    for (int c = 0; c < 2; ++c)
#pragma unroll
        for (int mi = 0; mi < 2; ++mi)
#pragma unroll
            for (int ni = 0; ni < 2; ++ni) acc[c][mi][ni] = (f32x4){0.f, 0.f, 0.f, 0.f};
#pragma unroll
    for (int ks = 0; ks < 64; ks += 32) {
        bf16x8 af[2], bfx[2];
#pragma unroll
        for (int mi = 0; mi < 2; ++mi)
            af[mi] = *(const bf16x8*)&sQ[(mi * 16 + lr) * 72 + ks + lk8];
#pragma unroll
        for (int ni = 0; ni < 2; ++ni)
            bfx[ni] = *(const bf16x8*)&sK[(wid * 32 + ni * 16 + lr) * 72 + ks + lk8];
#pragma unroll
        for (int mi = 0; mi < 2; ++mi)
#pragma unroll
            for (int ni = 0; ni < 2; ++ni)
                acc[0][mi][ni] = __builtin_amdgcn_mfma_f32_16x16x32_bf16(
                    af[mi], bfx[ni], acc[0][mi][ni], 0, 0, 0);
    }
    __syncthreads();
#pragma unroll
    for (int r = 0; r < 8; ++r) {
        int p = r * 256 + tid, j = p >> 4, d0 = (p & 15) * 4;
        *(ushort4*)&sK[j * 72 + d0] = kpre[r];
    }
    __syncthreads();
#pragma unroll
    for (int ks = 0; ks < 64; ks += 32) {
        bf16x8 af[2], bfx[2];
#pragma unroll
        for (int mi = 0; mi < 2; ++mi)
            af[mi] = *(const bf16x8*)&sQ[(mi * 16 + lr) * 72 + ks + lk8];
#pragma unroll
        for (int ni = 0; ni < 2; ++ni)
            bfx[ni] = *(const bf16x8*)&sK[(wid * 32 + ni * 16 + lr) * 72 + ks + lk8];
#pragma unroll
        for (int mi = 0; mi < 2; ++mi)
#pragma unroll
            for (int ni = 0; ni < 2; ++ni)
                acc[1][mi][ni] = __builtin_amdgcn_mfma_f32_16x16x32_bf16(
                    af[mi], bfx[ni], acc[1][mi][ni], 0, 0, 0);
    }
    __syncthreads();   // sK dead

    // ---- stage V chunk 0 (overlaps softmax part A) ----
#pragma unroll
    for (int r = 0; r < 8; ++r) {
        int p = r * 256 + tid, d = p >> 5, jc = (p & 31) * 4;
        *(ushort4*)&sVt[d * 136 + jc] =
            *(const ushort4*)&vhT[(((size_t)bh * DK_) + d) * N_ + jc];
    }
    // ---- softmax A: add bias, per-row max (in-reg + shuffle), cross-wave ----
#pragma unroll
    for (int c = 0; c < 2; ++c)
#pragma unroll
        for (int mi = 0; mi < 2; ++mi)
#pragma unroll
            for (int ni = 0; ni < 2; ++ni) {
                int col = c * 128 + wid * 32 + ni * 16 + lr;
#pragma unroll
                for (int reg = 0; reg < 4; ++reg) {
                    int row = mi * 16 + quad4 + reg;
                    acc[c][mi][ni][reg] += bf2f(sP[row * 264 + col]);
                }
            }
    float mrow[2][4];
#pragma unroll
    for (int mi = 0; mi < 2; ++mi)
#pragma unroll
        for (int reg = 0; reg < 4; ++reg) {
            float m = acc[0][mi][0][reg];
            m = fmaxf(m, acc[0][mi][1][reg]);
            m = fmaxf(m, acc[1][mi][0][reg]);
            m = fmaxf(m, acc[1][mi][1][reg]);
#pragma unroll
            for (int off = 1; off <= 8; off <<= 1) m = fmaxf(m, __shfl_xor(m, off, 64));
            mrow[mi][reg] = m;
        }
    if (lr == 0) {
#pragma unroll
        for (int mi = 0; mi < 2; ++mi)
#pragma unroll
            for (int reg = 0; reg < 4; ++reg)
                sRedM[(mi * 16 + quad4 + reg) * 4 + wid] = mrow[mi][reg];
    }
    __syncthreads();
    // ---- softmax B: global max, exp in place, per-row sum ----
    float gm[2][4], sl[2][4];
#pragma unroll
    for (int mi = 0; mi < 2; ++mi)
#pragma unroll
        for (int reg = 0; reg < 4; ++reg) {
            float4 mm = *(const float4*)&sRedM[(mi * 16 + quad4 + reg) * 4];
            gm[mi][reg] = fmaxf(fmaxf(mm.x, mm.y), fmaxf(mm.z, mm.w));
            sl[mi][reg] = 0.f;
        }
#pragma unroll
    for (int c = 0; c < 2; ++c)
#pragma unroll
        for (int mi = 0; mi < 2; ++mi)
#pragma unroll
            for (int ni = 0; ni < 2; ++ni)
#pragma unroll
                for (int reg = 0; reg < 4; ++reg) {
                    float e = __expf(acc[c][mi][ni][reg] - gm[mi][reg]);
                    acc[c][mi][ni][reg] = e;
                    sl[mi][reg] += e;
                }
#pragma unroll
    for (int mi = 0; mi < 2; ++mi)
#pragma unroll
        for (int reg = 0; reg < 4; ++reg) {
            float s = sl[mi][reg];
#pragma unroll
            for (int off = 1; off <= 8; off <<= 1) s += __shfl_xor(s, off, 64);
            sl[mi][reg] = s;
        }
    if (lr == 0) {
#pragma unroll
        for (int mi = 0; mi < 2; ++mi)
#pragma unroll
            for (int reg = 0; reg < 4; ++reg)
                sRedS[(mi * 16 + quad4 + reg) * 4 + wid] = sl[mi][reg];
    }
    __syncthreads();
    // ---- softmax C: normalize, write P (bf16) ----
#pragma unroll
    for (int mi = 0; mi < 2; ++mi)
#pragma unroll
        for (int reg = 0; reg < 4; ++reg) {
            float4 ss = *(const float4*)&sRedS[(mi * 16 + quad4 + reg) * 4];
            gm[mi][reg] = 1.0f / (ss.x + ss.y + ss.z + ss.w);   // reuse gm = inv
        }
#pragma unroll
    for (int c = 0; c < 2; ++c)
#pragma unroll
        for (int mi = 0; mi < 2; ++mi)
#pragma unroll
            for (int ni = 0; ni < 2; ++ni) {
                int col = c * 128 + wid * 32 + ni * 16 + lr;
#pragma unroll
                for (int reg = 0; reg < 4; ++reg) {
                    int row = mi * 16 + quad4 + reg;
                    sP[row * 264 + col] = f2bf(acc[c][mi][ni][reg] * gm[mi][reg]);
                }
            }
    __syncthreads();   // P + V0 committed

    // ---- PV chunk 0 ----
    f32x4 o[2];
    o[0] = (f32x4){0.f, 0.f, 0.f, 0.f};
    o[1] = (f32x4){0.f, 0.f, 0.f, 0.f};
#pragma unroll
    for (int k0 = 0; k0 < 128; k0 += 32) {
        bf16x8 bfx = *(const bf16x8*)&sVt[(wid * 16 + lr) * 136 + k0 + lk8];
#pragma unroll
        for (int mi = 0; mi < 2; ++mi) {
            bf16x8 af = *(const bf16x8*)&sP[(mi * 16 + lr) * 264 + k0 + lk8];
            o[mi] = __builtin_amdgcn_mfma_f32_16x16x32_bf16(af, bfx, o[mi], 0, 0, 0);
        }
    }
    __syncthreads();
    // ---- stage V chunk 1; PV chunk 1 ----
#pragma unroll
    for (int r = 0; r < 8; ++r) {
        int p = r * 256 + tid, d = p >> 5, jc = (p & 31) * 4;
        *(ushort4*)&sVt[d * 136 + jc] =
            *(const ushort4*)&vhT[(((size_t)bh * DK_) + d) * N_ + 128 + jc];
    }
    __syncthreads();
#pragma unroll
    for (int k0 = 0; k0 < 128; k0 += 32) {
        bf16x8 bfx = *(const bf16x8*)&sVt[(wid * 16 + lr) * 136 + k0 + lk8];
#pragma unroll
        for (int mi = 0; mi < 2; ++mi) {
            bf16x8 af = *(const bf16x8*)&sP[(mi * 16 + lr) * 264 + 128 + k0 + lk8];
            o[mi] = __builtin_amdgcn_mfma_f32_16x16x32_bf16(af, bfx, o[mi], 0, 0, 0);
        }
    }
#pragma unroll
    for (int mi = 0; mi < 2; ++mi)
#pragma unroll
        for (int reg = 0; reg < 4; ++reg) {
            int row = mi * 16 + quad4 + reg;
            attnb[((size_t)(b * N_ + i0 + row)) * D_ + h * 64 + wid * 16 + lr] =
                f2bf(o[mi][reg]);
        }
}

extern "C" void kernel_launch(void* const* d_in, const int* in_sizes, int n_in,
                              void* d_out, int out_size, void* d_ws, size_t ws_size,
                              hipStream_t stream) {
    const float* Xq = (const float*)d_in[0];
    const float* Xk = (const float*)d_in[1];
    const float* Xv = (const float*)d_in[2];
    const float* box = (const float*)d_in[3];
    const float* Wq = (const float*)d_in[4];
    const float* bq = (const float*)d_in[5];
    const float* Wk = (const float*)d_in[6];
    const float* bk = (const float*)d_in[7];
    const float* Wv = (const float*)d_in[8];
    const float* bv = (const float*)d_in[9];
    const float* Wo = (const float*)d_in[10];
    const float* bo = (const float*)d_in[11];
    const float* Wg = (const float*)d_in[12];
    const float* bg = (const float*)d_in[13];
    float* out = (float*)d_out;

    // ws (u16 units), 35.65 MB:
    //  [0,2M) qh  [2M,4M) kh  [4M,6M) vhT   [6M,14.39M) Sg
    //  [14M,16M) attnb   [16M,17M) Wt
    u16* ws16 = (u16*)d_ws;
    u16* qkv = ws16;
    u16* qh = qkv;
    u16* kh = qkv + 2097152;
    u16* vhT = qkv + 4194304;
    u16* Sg = ws16 + 6291456;
    u16* attnb = ws16 + 14680064;
    u16* Wt = ws16 + 16777216;

    dim3 blk(256);
    k_wtrans<<<dim3(16, 16, 4), blk, 0, stream>>>(Wq, Wk, Wv, Wo, Wt);
    k_gemm_qkv<<<dim3(8, 64, 3), blk, 0, stream>>>(Xq, Xk, Xv, Wt, bq, bk, bv, qkv);
    k_geo<<<dim3(B_ * N_), blk, 0, stream>>>(box, Wg, bg, Sg);
    k_attn<<<dim3(8, 128), blk, 0, stream>>>(qh, kh, vhT, Sg, attnb);
    k_gemm_out<<<dim3(8, 64), blk, 0, stream>>>(attnb, Wt + 3 * 262144, bo, out);
}

// Round 11
// 179.520 us; speedup vs baseline: 2.2904x; 1.0181x over previous
//
#include <hip/hip_runtime.h>
#include <hip/hip_bf16.h>

#define B_ 16
#define N_ 256
#define D_ 512
#define H_ 8
#define DK_ 64

typedef unsigned short u16;
typedef __attribute__((ext_vector_type(8))) short bf16x8;
typedef __attribute__((ext_vector_type(4))) float f32x4;

__device__ __forceinline__ float bf2f(u16 u) {
    union { unsigned int i; float f; } v;
    v.i = ((unsigned int)u) << 16;
    return v.f;
}
__device__ __forceinline__ u16 f2bf(float f) {
    union { float f; unsigned int i; } v;
    v.f = f;
    unsigned int x = v.i;
    unsigned int r = (x >> 16) & 1u;
    x += 0x7fffu + r;           // round-to-nearest-even
    return (u16)(x >> 16);
}

// ---------------------------------------------------------------------------
// k_prep: merged geo-bias (blocks 0..4095) + weight-transpose (4096..5119).
// geo: trig ONCE per (b,i,j) via native v_sin/v_cos (revolutions + fract
// range reduction — ~4 instr vs ~40 for libm sincos), dotted with all 8
// heads; writes log(clip(relu(wg),1e-6)) bf16 to Sg[B,H,N,N].
// wtrans: Wt[z][n][k](bf16) = W_z[k][n](f32).
// ---------------------------------------------------------------------------
__global__ __launch_bounds__(256) void k_prep(const float* __restrict__ box,
                                              const float* __restrict__ Wg,
                                              const float* __restrict__ bg,
                                              u16* __restrict__ Sg,
                                              const float* __restrict__ W0,
                                              const float* __restrict__ W1,
                                              const float* __restrict__ W2,
                                              const float* __restrict__ W3,
                                              u16* __restrict__ Wt) {
    const int tid = threadIdx.x;
    if (blockIdx.x < 4096) {
        // ---------------- geo part ----------------
        __shared__ float sWg[8][64];
        __shared__ float sbg[8];
        if (tid < 8) sbg[tid] = bg[tid];
        { int e = tid; sWg[e >> 6][e & 63] = Wg[e];
          e = tid + 256; sWg[e >> 6][e & 63] = Wg[e]; }
        const int bi = blockIdx.x, b = bi >> 8;
        float4 bxi = *(const float4*)&box[(size_t)bi * 4];
        float4 bxj = *(const float4*)&box[(size_t)(b * N_ + tid) * 4];
        __syncthreads();
        float cxi = (bxi.x + bxi.z) * 0.5f, cyi = (bxi.y + bxi.w) * 0.5f;
        float wi = bxi.z - bxi.x + 1.0f, hi = bxi.w - bxi.y + 1.0f;
        float cxj = (bxj.x + bxj.z) * 0.5f, cyj = (bxj.y + bxj.w) * 0.5f;
        float wj = bxj.z - bxj.x + 1.0f, hj = bxj.w - bxj.y + 1.0f;
        float pos[4];
        pos[0] = __logf(fmaxf(fabsf((cxi - cxj) / wi), 1e-3f));
        pos[1] = __logf(fmaxf(fabsf((cyi - cyj) / hi), 1e-3f));
        pos[2] = __logf(wi / wj);
        pos[3] = __logf(hi / hj);
        const float dm[8] = {1.0f, 0.42169650342858224f, 0.1778279410038923f,
                             0.07498942093324559f, 0.03162277660168379f,
                             0.013335214321633241f, 0.005623413251903491f,
                             0.0023713737056616554f};
        const float inv2pi = 0.15915494309189535f;
        float acc[8];
#pragma unroll
        for (int h = 0; h < 8; ++h) acc[h] = sbg[h];
#pragma unroll
        for (int t = 0; t < 4; ++t) {
            float base = 100.0f * pos[t];
#pragma unroll
            for (int f = 0; f < 8; ++f) {
                float rev = base * dm[f] * inv2pi;
                rev = rev - floorf(rev);           // range-reduce to [0,1)
                float sn = __builtin_amdgcn_sinf(rev);   // v_sin_f32 (revolutions)
                float cs = __builtin_amdgcn_cosf(rev);   // v_cos_f32
                int idx = t * 8 + f;
#pragma unroll
                for (int h = 0; h < 8; ++h)
                    acc[h] += sWg[h][idx] * sn + sWg[h][idx + 32] * cs;
            }
        }
        const int i = bi & 255;
#pragma unroll
        for (int h = 0; h < 8; ++h)
            Sg[(((size_t)(b * H_ + h) * N_) + i) * N_ + tid] =
                f2bf(__logf(fmaxf(acc[h], 1e-6f)));
    } else {
        // ---------------- wtrans part ----------------
        __shared__ float tt[32][33];
        int t = blockIdx.x - 4096;
        int z = t >> 8, yb = (t >> 4) & 15, xb = t & 15;
        const float* W = (z == 0) ? W0 : (z == 1) ? W1 : (z == 2) ? W2 : W3;
        u16* dst = Wt + (size_t)z * 262144;
        const int kb = yb * 32, nb = xb * 32;
#pragma unroll
        for (int r = 0; r < 4; ++r) {
            int p = r * 256 + tid;
            tt[p >> 5][p & 31] = W[(size_t)(kb + (p >> 5)) * 512 + nb + (p & 31)];
        }
        __syncthreads();
#pragma unroll
        for (int r = 0; r < 4; ++r) {
            int p = r * 256 + tid;
            dst[(size_t)(nb + (p >> 5)) * 512 + kb + (p & 31)] = f2bf(tt[p & 31][p >> 5]);
        }
    }
}

// ---------------------------------------------------------------------------
// k_gemm_qkv: f32 X read directly (cvt in staging), dbuf BK=64 MFMA core,
// LDS-bounce epilogue for coalesced stores.
//   z=0: qh[bh][row][dk] = ((X Wq)+bq) * 0.125 (exact pow2 scale)
//   z=1: kh[bh][row][dk]
//   z=2: vhT[bh][dk][row]  (transposed for attn's PV B-operand)
// ---------------------------------------------------------------------------
__global__ __launch_bounds__(256) void k_gemm_qkv(const float* __restrict__ Xq,
                                                  const float* __restrict__ Xk,
                                                  const float* __restrict__ Xv,
                                                  const u16* __restrict__ Wtb,
                                                  const float* __restrict__ bq,
                                                  const float* __restrict__ bk,
                                                  const float* __restrict__ bv,
                                                  u16* __restrict__ qkv) {
    const int z = blockIdx.z;
    const float* A = (z == 0) ? Xq : (z == 1) ? Xk : Xv;
    const u16* Wt = Wtb + (size_t)z * 262144;
    const float* bias = (z == 0) ? bq : (z == 1) ? bk : bv;
    u16* dst = qkv + (size_t)z * 2097152;

    __shared__ u16 As[2][64][72];
    __shared__ u16 Bs[2][64][72];
    const int tid = threadIdx.x;
    const int n0 = blockIdx.x * 64, m0 = blockIdx.y * 64;
    const int wid = tid >> 6, lane = tid & 63;
    const int wm = (wid & 1) * 32, wn = (wid >> 1) * 32;
    const int lr = lane & 15, lk8 = (lane >> 4) * 8, quad4 = (lane >> 4) * 4;

    f32x4 acc[2][2];
#pragma unroll
    for (int mi = 0; mi < 2; ++mi)
#pragma unroll
        for (int ni = 0; ni < 2; ++ni) acc[mi][ni] = (f32x4){0.f, 0.f, 0.f, 0.f};

    float4 raf[4];
    ushort4 rb[4];
#pragma unroll
    for (int r = 0; r < 4; ++r) {
        int p = r * 256 + tid, row = p >> 4, c4 = (p & 15) * 4;
        raf[r] = *(const float4*)&A[(size_t)(m0 + row) * 512 + c4];
        rb[r] = *(const ushort4*)&Wt[(size_t)(n0 + row) * 512 + c4];
    }
#pragma unroll
    for (int r = 0; r < 4; ++r) {
        int p = r * 256 + tid, row = p >> 4, c4 = (p & 15) * 4;
        ushort4 ab;
        ab.x = f2bf(raf[r].x); ab.y = f2bf(raf[r].y);
        ab.z = f2bf(raf[r].z); ab.w = f2bf(raf[r].w);
        *(ushort4*)&As[0][row][c4] = ab;
        *(ushort4*)&Bs[0][row][c4] = rb[r];
    }
    __syncthreads();
    for (int it = 0; it < 8; ++it) {
        const int cur = it & 1;
        if (it < 7) {
            int k0n = (it + 1) * 64;
#pragma unroll
            for (int r = 0; r < 4; ++r) {
                int p = r * 256 + tid, row = p >> 4, c4 = (p & 15) * 4;
                raf[r] = *(const float4*)&A[(size_t)(m0 + row) * 512 + k0n + c4];
                rb[r] = *(const ushort4*)&Wt[(size_t)(n0 + row) * 512 + k0n + c4];
            }
        }
#pragma unroll
        for (int ks = 0; ks < 64; ks += 32) {
            bf16x8 af[2], bfx[2];
#pragma unroll
            for (int mi = 0; mi < 2; ++mi)
                af[mi] = *(const bf16x8*)&As[cur][wm + mi * 16 + lr][ks + lk8];
#pragma unroll
            for (int ni = 0; ni < 2; ++ni)
                bfx[ni] = *(const bf16x8*)&Bs[cur][wn + ni * 16 + lr][ks + lk8];
#pragma unroll
            for (int mi = 0; mi < 2; ++mi)
#pragma unroll
                for (int ni = 0; ni < 2; ++ni)
                    acc[mi][ni] = __builtin_amdgcn_mfma_f32_16x16x32_bf16(
                        af[mi], bfx[ni], acc[mi][ni], 0, 0, 0);
        }
        if (it < 7) {
#pragma unroll
            for (int r = 0; r < 4; ++r) {
                int p = r * 256 + tid, row = p >> 4, c4 = (p & 15) * 4;
                ushort4 ab;
                ab.x = f2bf(raf[r].x); ab.y = f2bf(raf[r].y);
                ab.z = f2bf(raf[r].z); ab.w = f2bf(raf[r].w);
                *(ushort4*)&As[1 - cur][row][c4] = ab;
                *(ushort4*)&Bs[1 - cur][row][c4] = rb[r];
            }
            __syncthreads();
        }
    }
    // ---- epilogue via LDS bounce (As[0] is safe to overwrite) ----
    u16* bounce = &As[0][0][0];   // [64][72]
    const float scale = (z == 0) ? 0.125f : 1.0f;
    const int h = n0 >> 6, b = m0 >> 8, rrb = m0 & 255;
    if (z == 2) {
        // transposed: bounce[cn][rm]
#pragma unroll
        for (int mi = 0; mi < 2; ++mi)
#pragma unroll
            for (int ni = 0; ni < 2; ++ni) {
                int cn = wn + ni * 16 + lr;
                float bb = bias[n0 + cn];
#pragma unroll
                for (int reg = 0; reg < 4; ++reg) {
                    int rm = wm + mi * 16 + quad4 + reg;
                    bounce[cn * 72 + rm] = f2bf(acc[mi][ni][reg] + bb);
                }
            }
        __syncthreads();
#pragma unroll
        for (int r = 0; r < 4; ++r) {
            int p = r * 256 + tid, dn = p >> 4, c4 = (p & 15) * 4;
            *(ushort4*)&dst[(((size_t)(b * H_ + h) * DK_) + dn) * N_ + rrb + c4] =
                *(const ushort4*)&bounce[dn * 72 + c4];
        }
    } else {
        // row-major: bounce[rm][cn]
#pragma unroll
        for (int mi = 0; mi < 2; ++mi)
#pragma unroll
            for (int ni = 0; ni < 2; ++ni) {
                int cn = wn + ni * 16 + lr;
                float bb = bias[n0 + cn];
#pragma unroll
                for (int reg = 0; reg < 4; ++reg) {
                    int rm = wm + mi * 16 + quad4 + reg;
                    bounce[rm * 72 + cn] = f2bf((acc[mi][ni][reg] + bb) * scale);
                }
            }
        __syncthreads();
#pragma unroll
        for (int r = 0; r < 4; ++r) {
            int p = r * 256 + tid, rm = p >> 4, c4 = (p & 15) * 4;
            *(ushort4*)&dst[(((size_t)(b * H_ + h) * N_) + rrb + rm) * DK_ + c4] =
                *(const ushort4*)&bounce[rm * 72 + c4];
        }
    }
}

// ---------------------------------------------------------------------------
// k_gemm_out: out(f32) = attnb(bf16) @ Wot^T + bo (dbuf core, f32 stores are
// already coalesced 64B/quad).
// ---------------------------------------------------------------------------
__global__ __launch_bounds__(256) void k_gemm_out(const u16* __restrict__ Ab,
                                                  const u16* __restrict__ Wt,
                                                  const float* __restrict__ bias,
                                                  float* __restrict__ outp) {
    __shared__ u16 As[2][64][72];
    __shared__ u16 Bs[2][64][72];
    const int tid = threadIdx.x;
    const int n0 = blockIdx.x * 64, m0 = blockIdx.y * 64;
    const int wid = tid >> 6, lane = tid & 63;
    const int wm = (wid & 1) * 32, wn = (wid >> 1) * 32;
    const int lr = lane & 15, lk8 = (lane >> 4) * 8;
    f32x4 acc[2][2];
#pragma unroll
    for (int mi = 0; mi < 2; ++mi)
#pragma unroll
        for (int ni = 0; ni < 2; ++ni) acc[mi][ni] = (f32x4){0.f, 0.f, 0.f, 0.f};
    ushort4 ra[4], rb[4];
#pragma unroll
    for (int r = 0; r < 4; ++r) {
        int p = r * 256 + tid, row = p >> 4, c4 = (p & 15) * 4;
        ra[r] = *(const ushort4*)&Ab[(size_t)(m0 + row) * 512 + c4];
        rb[r] = *(const ushort4*)&Wt[(size_t)(n0 + row) * 512 + c4];
    }
#pragma unroll
    for (int r = 0; r < 4; ++r) {
        int p = r * 256 + tid, row = p >> 4, c4 = (p & 15) * 4;
        *(ushort4*)&As[0][row][c4] = ra[r];
        *(ushort4*)&Bs[0][row][c4] = rb[r];
    }
    __syncthreads();
    for (int it = 0; it < 8; ++it) {
        const int cur = it & 1;
        if (it < 7) {
            int k0n = (it + 1) * 64;
#pragma unroll
            for (int r = 0; r < 4; ++r) {
                int p = r * 256 + tid, row = p >> 4, c4 = (p & 15) * 4;
                ra[r] = *(const ushort4*)&Ab[(size_t)(m0 + row) * 512 + k0n + c4];
                rb[r] = *(const ushort4*)&Wt[(size_t)(n0 + row) * 512 + k0n + c4];
            }
        }
#pragma unroll
        for (int ks = 0; ks < 64; ks += 32) {
            bf16x8 af[2], bfx[2];
#pragma unroll
            for (int mi = 0; mi < 2; ++mi)
                af[mi] = *(const bf16x8*)&As[cur][wm + mi * 16 + lr][ks + lk8];
#pragma unroll
            for (int ni = 0; ni < 2; ++ni)
                bfx[ni] = *(const bf16x8*)&Bs[cur][wn + ni * 16 + lr][ks + lk8];
#pragma unroll
            for (int mi = 0; mi < 2; ++mi)
#pragma unroll
                for (int ni = 0; ni < 2; ++ni)
                    acc[mi][ni] = __builtin_amdgcn_mfma_f32_16x16x32_bf16(
                        af[mi], bfx[ni], acc[mi][ni], 0, 0, 0);
        }
        if (it < 7) {
#pragma unroll
            for (int r = 0; r < 4; ++r) {
                int p = r * 256 + tid, row = p >> 4, c4 = (p & 15) * 4;
                *(ushort4*)&As[1 - cur][row][c4] = ra[r];
                *(ushort4*)&Bs[1 - cur][row][c4] = rb[r];
            }
            __syncthreads();
        }
    }
#pragma unroll
    for (int mi = 0; mi < 2; ++mi)
#pragma unroll
        for (int ni = 0; ni < 2; ++ni) {
            int col = n0 + wn + ni * 16 + lr;
            float bb = bias[col];
#pragma unroll
            for (int reg = 0; reg < 4; ++reg) {
                int m = m0 + wm + mi * 16 + (lane >> 4) * 4 + reg;
                outp[(size_t)m * 512 + col] = acc[mi][ni][reg] + bb;
            }
        }
}

// ---------------------------------------------------------------------------
// k_attn v3: S in accumulators; in-register softmax (shuffle + 1KB LDS cross-
// wave reduce); bias preloaded; K/V in 128-chunks; V pre-transposed input.
// LDS 40,960 B -> 4 blocks/CU.
// ---------------------------------------------------------------------------
__global__ __launch_bounds__(256) void k_attn(const u16* __restrict__ qh,
                                              const u16* __restrict__ kh,
                                              const u16* __restrict__ vhT,
                                              const u16* __restrict__ Sg,
                                              u16* __restrict__ attnb) {
    __shared__ __align__(16) unsigned char smem[40960];
    u16* sQ = (u16*)smem;                     // [32][72]  (4608 B)
    u16* sP = (u16*)(smem + 4608);            // [32][264] (16896 B): bias -> P
    u16* sK = (u16*)(smem + 21504);           // [128][72] (18432 B), aliased:
    u16* sVt = (u16*)(smem + 21504);          // [64][136] (17408 B)
    float* sRedM = (float*)(smem + 39936);    // [32][4]
    float* sRedS = (float*)(smem + 40448);    // [32][4]

    const int tid = threadIdx.x;
    const int i0 = blockIdx.x * 32;
    const int bh = blockIdx.y;
    const int b = bh >> 3, h = bh & 7;
    const int wid = tid >> 6, lane = tid & 63;
    const int lr = lane & 15, lk8 = (lane >> 4) * 8, quad4 = (lane >> 4) * 4;

    // ---- stage Q, bias, K chunk 0 ----
#pragma unroll
    for (int r = 0; r < 2; ++r) {
        int p = r * 256 + tid, i = p >> 4, d0 = (p & 15) * 4;
        *(ushort4*)&sQ[i * 72 + d0] =
            *(const ushort4*)&qh[((size_t)bh * N_ + i0 + i) * DK_ + d0];
    }
#pragma unroll
    for (int r = 0; r < 8; ++r) {
        int p = r * 256 + tid, row = p >> 6, jc = (p & 63) * 4;
        *(ushort4*)&sP[row * 264 + jc] =
            *(const ushort4*)&Sg[(((size_t)bh * N_) + i0 + row) * N_ + jc];
    }
#pragma unroll
    for (int r = 0; r < 8; ++r) {
        int p = r * 256 + tid, j = p >> 4, d0 = (p & 15) * 4;
        *(ushort4*)&sK[j * 72 + d0] =
            *(const ushort4*)&kh[((size_t)bh * N_ + j) * DK_ + d0];
    }
    __syncthreads();

    // ---- K chunk-1 prefetch into regs; QK^T chunk 0 ----
    ushort4 kpre[8];
#pragma unroll
    for (int r = 0; r < 8; ++r) {
        int p = r * 256 + tid, j = p >> 4, d0 = (p & 15) * 4;
        kpre[r] = *(const ushort4*)&kh[((size_t)bh * N_ + 128 + j) * DK_ + d0];
    }
    f32x4 acc[2][2][2];   // [chunk][mi][ni]
#pragma unroll
    for (int c = 0; c < 2; ++c)
#pragma unroll
        for (int mi = 0; mi < 2; ++mi)
#pragma unroll
            for (int ni = 0; ni < 2; ++ni) acc[c][mi][ni] = (f32x4){0.f, 0.f, 0.f, 0.f};
#pragma unroll
    for (int ks = 0; ks < 64; ks += 32) {
        bf16x8 af[2], bfx[2];
#pragma unroll
        for (int mi = 0; mi < 2; ++mi)
            af[mi] = *(const bf16x8*)&sQ[(mi * 16 + lr) * 72 + ks + lk8];
#pragma unroll
        for (int ni = 0; ni < 2; ++ni)
            bfx[ni] = *(const bf16x8*)&sK[(wid * 32 + ni * 16 + lr) * 72 + ks + lk8];
#pragma unroll
        for (int mi = 0; mi < 2; ++mi)
#pragma unroll
            for (int ni = 0; ni < 2; ++ni)
                acc[0][mi][ni] = __builtin_amdgcn_mfma_f32_16x16x32_bf16(
                    af[mi], bfx[ni], acc[0][mi][ni], 0, 0, 0);
    }
    __syncthreads();
#pragma unroll
    for (int r = 0; r < 8; ++r) {
        int p = r * 256 + tid, j = p >> 4, d0 = (p & 15) * 4;
        *(ushort4*)&sK[j * 72 + d0] = kpre[r];
    }
    __syncthreads();
#pragma unroll
    for (int ks = 0; ks < 64; ks += 32) {
        bf16x8 af[2], bfx[2];
#pragma unroll
        for (int mi = 0; mi < 2; ++mi)
            af[mi] = *(const bf16x8*)&sQ[(mi * 16 + lr) * 72 + ks + lk8];
#pragma unroll
        for (int ni = 0; ni < 2; ++ni)
            bfx[ni] = *(const bf16x8*)&sK[(wid * 32 + ni * 16 + lr) * 72 + ks + lk8];
#pragma unroll
        for (int mi = 0; mi < 2; ++mi)
#pragma unroll
            for (int ni = 0; ni < 2; ++ni)
                acc[1][mi][ni] = __builtin_amdgcn_mfma_f32_16x16x32_bf16(
                    af[mi], bfx[ni], acc[1][mi][ni], 0, 0, 0);
    }
    __syncthreads();   // sK dead

    // ---- stage V chunk 0 (overlaps softmax part A) ----
#pragma unroll
    for (int r = 0; r < 8; ++r) {
        int p = r * 256 + tid, d = p >> 5, jc = (p & 31) * 4;
        *(ushort4*)&sVt[d * 136 + jc] =
            *(const ushort4*)&vhT[(((size_t)bh * DK_) + d) * N_ + jc];
    }
    // ---- softmax A: add bias, per-row max (in-reg + shuffle), cross-wave ----
#pragma unroll
    for (int c = 0; c < 2; ++c)
#pragma unroll
        for (int mi = 0; mi < 2; ++mi)
#pragma unroll
            for (int ni = 0; ni < 2; ++ni) {
                int col = c * 128 + wid * 32 + ni * 16 + lr;
#pragma unroll
                for (int reg = 0; reg < 4; ++reg) {
                    int row = mi * 16 + quad4 + reg;
                    acc[c][mi][ni][reg] += bf2f(sP[row * 264 + col]);
                }
            }
    float mrow[2][4];
#pragma unroll
    for (int mi = 0; mi < 2; ++mi)
#pragma unroll
        for (int reg = 0; reg < 4; ++reg) {
            float m = acc[0][mi][0][reg];
            m = fmaxf(m, acc[0][mi][1][reg]);
            m = fmaxf(m, acc[1][mi][0][reg]);
            m = fmaxf(m, acc[1][mi][1][reg]);
#pragma unroll
            for (int off = 1; off <= 8; off <<= 1) m = fmaxf(m, __shfl_xor(m, off, 64));
            mrow[mi][reg] = m;
        }
    if (lr == 0) {
#pragma unroll
        for (int mi = 0; mi < 2; ++mi)
#pragma unroll
            for (int reg = 0; reg < 4; ++reg)
                sRedM[(mi * 16 + quad4 + reg) * 4 + wid] = mrow[mi][reg];
    }
    __syncthreads();
    // ---- softmax B: global max, exp in place, per-row sum ----
    float gm[2][4], sl[2][4];
#pragma unroll
    for (int mi = 0; mi < 2; ++mi)
#pragma unroll
        for (int reg = 0; reg < 4; ++reg) {
            float4 mm = *(const float4*)&sRedM[(mi * 16 + quad4 + reg) * 4];
            gm[mi][reg] = fmaxf(fmaxf(mm.x, mm.y), fmaxf(mm.z, mm.w));
            sl[mi][reg] = 0.f;
        }
#pragma unroll
    for (int c = 0; c < 2; ++c)
#pragma unroll
        for (int mi = 0; mi < 2; ++mi)
#pragma unroll
            for (int ni = 0; ni < 2; ++ni)
#pragma unroll
                for (int reg = 0; reg < 4; ++reg) {
                    float e = __expf(acc[c][mi][ni][reg] - gm[mi][reg]);
                    acc[c][mi][ni][reg] = e;
                    sl[mi][reg] += e;
                }
#pragma unroll
    for (int mi = 0; mi < 2; ++mi)
#pragma unroll
        for (int reg = 0; reg < 4; ++reg) {
            float s = sl[mi][reg];
#pragma unroll
            for (int off = 1; off <= 8; off <<= 1) s += __shfl_xor(s, off, 64);
            sl[mi][reg] = s;
        }
    if (lr == 0) {
#pragma unroll
        for (int mi = 0; mi < 2; ++mi)
#pragma unroll
            for (int reg = 0; reg < 4; ++reg)
                sRedS[(mi * 16 + quad4 + reg) * 4 + wid] = sl[mi][reg];
    }
    __syncthreads();
    // ---- softmax C: normalize, write P (bf16) ----
#pragma unroll
    for (int mi = 0; mi < 2; ++mi)
#pragma unroll
        for (int reg = 0; reg < 4; ++reg) {
            float4 ss = *(const float4*)&sRedS[(mi * 16 + quad4 + reg) * 4];
            gm[mi][reg] = 1.0f / (ss.x + ss.y + ss.z + ss.w);   // reuse gm = inv
        }
#pragma unroll
    for (int c = 0; c < 2; ++c)
#pragma unroll
        for (int mi = 0; mi < 2; ++mi)
#pragma unroll
            for (int ni = 0; ni < 2; ++ni) {
                int col = c * 128 + wid * 32 + ni * 16 + lr;
#pragma unroll
                for (int reg = 0; reg < 4; ++reg) {
                    int row = mi * 16 + quad4 + reg;
                    sP[row * 264 + col] = f2bf(acc[c][mi][ni][reg] * gm[mi][reg]);
                }
            }
    __syncthreads();   // P + V0 committed

    // ---- PV chunk 0 ----
    f32x4 o[2];
    o[0] = (f32x4){0.f, 0.f, 0.f, 0.f};
    o[1] = (f32x4){0.f, 0.f, 0.f, 0.f};
#pragma unroll
    for (int k0 = 0; k0 < 128; k0 += 32) {
        bf16x8 bfx = *(const bf16x8*)&sVt[(wid * 16 + lr) * 136 + k0 + lk8];
#pragma unroll
        for (int mi = 0; mi < 2; ++mi) {
            bf16x8 af = *(const bf16x8*)&sP[(mi * 16 + lr) * 264 + k0 + lk8];
            o[mi] = __builtin_amdgcn_mfma_f32_16x16x32_bf16(af, bfx, o[mi], 0, 0, 0);
        }
    }
    __syncthreads();
    // ---- stage V chunk 1; PV chunk 1 ----
#pragma unroll
    for (int r = 0; r < 8; ++r) {
        int p = r * 256 + tid, d = p >> 5, jc = (p & 31) * 4;
        *(ushort4*)&sVt[d * 136 + jc] =
            *(const ushort4*)&vhT[(((size_t)bh * DK_) + d) * N_ + 128 + jc];
    }
    __syncthreads();
#pragma unroll
    for (int k0 = 0; k0 < 128; k0 += 32) {
        bf16x8 bfx = *(const bf16x8*)&sVt[(wid * 16 + lr) * 136 + k0 + lk8];
#pragma unroll
        for (int mi = 0; mi < 2; ++mi) {
            bf16x8 af = *(const bf16x8*)&sP[(mi * 16 + lr) * 264 + 128 + k0 + lk8];
            o[mi] = __builtin_amdgcn_mfma_f32_16x16x32_bf16(af, bfx, o[mi], 0, 0, 0);
        }
    }
#pragma unroll
    for (int mi = 0; mi < 2; ++mi)
#pragma unroll
        for (int reg = 0; reg < 4; ++reg) {
            int row = mi * 16 + quad4 + reg;
            attnb[((size_t)(b * N_ + i0 + row)) * D_ + h * 64 + wid * 16 + lr] =
                f2bf(o[mi][reg]);
        }
}

extern "C" void kernel_launch(void* const* d_in, const int* in_sizes, int n_in,
                              void* d_out, int out_size, void* d_ws, size_t ws_size,
                              hipStream_t stream) {
    const float* Xq = (const float*)d_in[0];
    const float* Xk = (const float*)d_in[1];
    const float* Xv = (const float*)d_in[2];
    const float* box = (const float*)d_in[3];
    const float* Wq = (const float*)d_in[4];
    const float* bq = (const float*)d_in[5];
    const float* Wk = (const float*)d_in[6];
    const float* bk = (const float*)d_in[7];
    const float* Wv = (const float*)d_in[8];
    const float* bv = (const float*)d_in[9];
    const float* Wo = (const float*)d_in[10];
    const float* bo = (const float*)d_in[11];
    const float* Wg = (const float*)d_in[12];
    const float* bg = (const float*)d_in[13];
    float* out = (float*)d_out;

    // ws (u16 units), 35.65 MB:
    //  [0,2M) qh  [2M,4M) kh  [4M,6M) vhT   [6M,14.39M) Sg
    //  [14M,16M) attnb   [16M,17M) Wt
    u16* ws16 = (u16*)d_ws;
    u16* qkv = ws16;
    u16* qh = qkv;
    u16* kh = qkv + 2097152;
    u16* vhT = qkv + 4194304;
    u16* Sg = ws16 + 6291456;
    u16* attnb = ws16 + 14680064;
    u16* Wt = ws16 + 16777216;

    dim3 blk(256);
    k_prep<<<dim3(5120), blk, 0, stream>>>(box, Wg, bg, Sg, Wq, Wk, Wv, Wo, Wt);
    k_gemm_qkv<<<dim3(8, 64, 3), blk, 0, stream>>>(Xq, Xk, Xv, Wt, bq, bk, bv, qkv);
    k_attn<<<dim3(8, 128), blk, 0, stream>>>(qh, kh, vhT, Sg, attnb);
    k_gemm_out<<<dim3(8, 64), blk, 0, stream>>>(attnb, Wt + 3 * 262144, bo, out);
}